// Round 3
// baseline (184.397 us; speedup 1.0000x reference)
//
#include <hip/hip_runtime.h>
#include <hip/hip_bf16.h>
#include <hip/hip_fp16.h>

// DenseGAT fused kernel for MI355X.
// N=4096, IN=256, HEADS=8, D=64, C=512.
// logits are rank-1 per head + shared adjacency mask => no QK GEMM.
// Round 3: adjacency -> 2MB bitmask pre-pass (merged with proj dispatch);
// attn inner loop is barrier-free (mask LDS-resident, Hpack/ddata from L2).
//
// ws layout:
//   Hpack : _Float16 [8][128][4][64][8] @ 0      (4 MB)   H in B-frag order
//   maskw : uint     [4096][128]        @ 4MB    (2 MB)   bit j&31 of word j>>5
//   ddata : float    [8][4096][2]       @ 6MB    (256 KB) {d*log2e, 0.2d*log2e}
//   esrc  : float    [4096][8]          @ 6.25MB (128 KB)
//   dmax  : uint     [8]                @ 6.375MB

#define GAT_N 4096
#define GAT_K 256
#define GAT_C 512
#define GAT_H 8
#define L2E 1.4426950408889634f

typedef _Float16 v8h __attribute__((ext_vector_type(8)));
typedef float v4f __attribute__((ext_vector_type(4)));
typedef int v4i __attribute__((ext_vector_type(4)));

static __device__ inline v4f mfma16(v8h a, v8h b, v4f c) {
    return __builtin_amdgcn_mfma_f32_16x16x32_f16(a, b, c, 0, 0, 0);
}

// -------- Phase A: projection + e_src/e_dst + Hpack, PLUS bitmask build ------
// grid 2560: blocks 0..511 = proj (64 mtiles x 8 heads), 512..2559 = mask.
__global__ __launch_bounds__(256) void gat_prep(
    const float* __restrict__ x, const float* __restrict__ W,
    const float* __restrict__ asrc, const float* __restrict__ adst,
    const int* __restrict__ adj,
    _Float16* __restrict__ Hpack, float* __restrict__ ddata,
    float* __restrict__ esrc, unsigned* __restrict__ dmax,
    unsigned* __restrict__ maskw)
{
    const int bid = blockIdx.x;
    const int tid = threadIdx.x;

    if (bid >= 512) {
        // ---- bitmask path: one thread builds one 32-bit mask word ----
        const int idx = (bid - 512) * 256 + tid;        // 0 .. 524287
        const int* p = adj + (size_t)idx * 32;
        unsigned word = 0;
#pragma unroll
        for (int k = 0; k < 8; ++k) {
            v4i v = __builtin_nontemporal_load((const v4i*)(p + k * 4));
            word |= (unsigned)(v.x > 0) << (k * 4 + 0);
            word |= (unsigned)(v.y > 0) << (k * 4 + 1);
            word |= (unsigned)(v.z > 0) << (k * 4 + 2);
            word |= (unsigned)(v.w > 0) << (k * 4 + 3);
        }
        maskw[idx] = word;
        return;
    }

    // ---- projection path ----
    const int head = bid & 7, mtile = bid >> 3;
    const int wv = tid >> 6, l = tid & 63;
    const int dlow = l & 15, q = l >> 4;
    const int rowbase = mtile * 64 + wv * 16;
    const int arow = rowbase + dlow;

    v4f acc[4] = {};
#pragma unroll
    for (int kc = 0; kc < 8; ++kc) {
        const int k0 = kc * 32 + q * 8;
        const float4* ap = (const float4*)(x + (size_t)arow * GAT_K + k0);
        float4 xa = ap[0], xb = ap[1];
        v8h af;
        af[0] = (_Float16)xa.x; af[1] = (_Float16)xa.y; af[2] = (_Float16)xa.z; af[3] = (_Float16)xa.w;
        af[4] = (_Float16)xb.x; af[5] = (_Float16)xb.y; af[6] = (_Float16)xb.z; af[7] = (_Float16)xb.w;
#pragma unroll
        for (int nt = 0; nt < 4; ++nt) {
            const int c = head * 64 + nt * 16 + dlow;
            const float4* bp = (const float4*)(W + (size_t)c * GAT_K + k0);
            float4 wa = bp[0], wb = bp[1];
            v8h bf;
            bf[0] = (_Float16)wa.x; bf[1] = (_Float16)wa.y; bf[2] = (_Float16)wa.z; bf[3] = (_Float16)wa.w;
            bf[4] = (_Float16)wb.x; bf[5] = (_Float16)wb.y; bf[6] = (_Float16)wb.z; bf[7] = (_Float16)wb.w;
            acc[nt] = mfma16(af, bf, acc[nt]);
        }
    }

    float as[4], ad[4];
#pragma unroll
    for (int nt = 0; nt < 4; ++nt) {
        const int d = nt * 16 + dlow;
        as[nt] = asrc[head * 64 + d];
        ad[nt] = adst[head * 64 + d];
    }
    float es[4], ed[4];
#pragma unroll
    for (int r = 0; r < 4; ++r) {
        float se = 0.f, de = 0.f;
#pragma unroll
        for (int nt = 0; nt < 4; ++nt) { se += acc[nt][r] * as[nt]; de += acc[nt][r] * ad[nt]; }
#pragma unroll
        for (int m = 1; m < 16; m <<= 1) { se += __shfl_xor(se, m); de += __shfl_xor(de, m); }
        es[r] = se; ed[r] = de;
    }
    if (dlow == 0) {
#pragma unroll
        for (int r = 0; r < 4; ++r) {
            const int j = rowbase + q * 4 + r;
            esrc[j * GAT_H + head] = es[r];
            ((float2*)ddata)[(size_t)head * GAT_N + j] = make_float2(ed[r] * L2E, 0.2f * L2E * ed[r]);
        }
        float mx = fmaxf(fmaxf(ed[0], ed[1]), fmaxf(ed[2], ed[3]));
        unsigned u = __float_as_uint(mx);
        unsigned enc = (u & 0x80000000u) ? ~u : (u | 0x80000000u);
        atomicMax(dmax + head, enc);
    }

    // Hpack: element (j, d) -> [head][j>>5][nt][(p>>3)*16 + dlow][p&7], p=j&31.
    const int jc = rowbase >> 5;
    const int p16 = rowbase & 16;
#pragma unroll
    for (int nt = 0; nt < 4; ++nt) {
#pragma unroll
        for (int rp = 0; rp < 4; rp += 2) {
            const int p = p16 + q * 4 + rp;
            const int qp = p >> 3, e = p & 7;
            const int lanep = qp * 16 + dlow;
            const size_t idx = ((((size_t)head * 128 + jc) * 4 + nt) * 64 + lanep) * 8 + e;
            union { unsigned u; _Float16 h[2]; } pk;
            pk.h[0] = (_Float16)acc[nt][rp];
            pk.h[1] = (_Float16)acc[nt][rp + 1];
            *(unsigned*)(Hpack + idx) = pk.u;
        }
    }
}

// ---------------- Phase B: fused mask + softmax + alpha@H -------------------
// grid 256; XCD-partitioned: xcd = bid&7, hg = xcd>>2, it = (bid>>3)*4 | (xcd&3).
// block 512 (8 waves): wave wv -> head = hg*4 + (wv>>1), parity = wv&1.
// Inner loop: NO barriers, NO global staging — mask from LDS, Hpack/ddata L2.
__global__ __launch_bounds__(512) void gat_attn(
    const unsigned* __restrict__ maskw, const _Float16* __restrict__ Hpack,
    const float* __restrict__ ddata, const float* __restrict__ esrc,
    const unsigned* __restrict__ dmax, const float* __restrict__ bias,
    float* __restrict__ out)
{
    // mldsT[128 words][32 rows] (16KB) unioned with xchg[4][64*41] (41984 B)
    __shared__ __align__(16) char smem[4 * 64 * 41 * 4];
    unsigned (*mldsT)[32] = (unsigned (*)[32])smem;
    float* xchg = (float*)smem;

    const int bid = blockIdx.x;
    const int xcd = bid & 7;
    const int hg = xcd >> 2;
    const int it = ((bid >> 3) << 2) | (xcd & 3);
    const int tid = threadIdx.x;
    const int wv = tid >> 6, l = tid & 63;
    const int head = hg * 4 + (wv >> 1), par = wv & 1;
    const int dlow = l & 15, q = l >> 4;
    const int ibase = it * 32;

    // load 32-row mask, transposed into LDS: mldsT[w][r]
    {
        const int r = tid >> 4, wb = (tid & 15) * 8;
        const v4i* mp = (const v4i*)(maskw + (size_t)(ibase + r) * 128 + wb);
        v4i a = mp[0], b = mp[1];
        mldsT[wb + 0][r] = (unsigned)a.x; mldsT[wb + 1][r] = (unsigned)a.y;
        mldsT[wb + 2][r] = (unsigned)a.z; mldsT[wb + 3][r] = (unsigned)a.w;
        mldsT[wb + 4][r] = (unsigned)b.x; mldsT[wb + 5][r] = (unsigned)b.y;
        mldsT[wb + 6][r] = (unsigned)b.z; mldsT[wb + 7][r] = (unsigned)b.w;
    }

    // per-row constants: a1 = (s-M)*log2e, a2 = (0.2s-M)*log2e, M = leaky(s+Dmax)
    const unsigned du = dmax[head];
    const float Dm = __uint_as_float((du & 0x80000000u) ? (du & 0x7fffffffu) : ~du);
    float a1[2], a2[2];
#pragma unroll
    for (int rt = 0; rt < 2; ++rt) {
        const int i = ibase + rt * 16 + dlow;
        const float s = esrc[i * GAT_H + head];
        const float sm = s + Dm;
        const float M = fmaxf(sm, 0.2f * sm);
        a1[rt] = (s - M) * L2E;
        a2[rt] = (0.2f * s - M) * L2E;
    }

    v4f accW[2][4] = {};
    v4f accZ[2] = {};
    v8h ones;
#pragma unroll
    for (int e = 0; e < 8; ++e) ones[e] = (_Float16)1.0f;

    __syncthreads();   // mask visible; last barrier until epilogue

#pragma unroll 2
    for (int t = 0; t < 32; ++t) {
#pragma unroll
        for (int kc = 0; kc < 2; ++kc) {
            const int jc = t * 4 + par * 2 + kc;          // 32-j chunk index
            const int kg = (jc << 5) + q * 8;             // this lane's first j
            const unsigned mw0 = mldsT[jc][dlow];
            const unsigned mw1 = mldsT[jc][dlow + 16];
            const unsigned b0 = (mw0 >> (q * 8)) & 255u;
            const unsigned b1 = (mw1 >> (q * 8)) & 255u;

            const float4* dp = (const float4*)(ddata + ((size_t)head * GAT_N + kg) * 2);
            float4 d0 = dp[0], d1 = dp[1], d2 = dp[2], d3 = dp[3];

            v8h fr0, fr1;
#define GAT_PB(E, DD1, DD2) {                                           \
                float m0 = (float)((b0 >> (E)) & 1u);                   \
                float m1 = (float)((b1 >> (E)) & 1u);                   \
                float t0 = fmaxf((DD1) + a1[0], (DD2) + a2[0]);         \
                float t1 = fmaxf((DD1) + a1[1], (DD2) + a2[1]);         \
                fr0[E] = (_Float16)(__builtin_amdgcn_exp2f(t0) * m0);   \
                fr1[E] = (_Float16)(__builtin_amdgcn_exp2f(t1) * m1); }
            GAT_PB(0, d0.x, d0.y)
            GAT_PB(1, d0.z, d0.w)
            GAT_PB(2, d1.x, d1.y)
            GAT_PB(3, d1.z, d1.w)
            GAT_PB(4, d2.x, d2.y)
            GAT_PB(5, d2.z, d2.w)
            GAT_PB(6, d3.x, d3.y)
            GAT_PB(7, d3.z, d3.w)
#undef GAT_PB

#pragma unroll
            for (int nt = 0; nt < 4; ++nt) {
                const v8h bf = *(const v8h*)(Hpack + ((((size_t)head * 128 + jc) * 4 + nt) * 64 + l) * 8);
                accW[0][nt] = mfma16(fr0, bf, accW[0][nt]);
                accW[1][nt] = mfma16(fr1, bf, accW[1][nt]);
            }
            accZ[0] = mfma16(fr0, ones, accZ[0]);
            accZ[1] = mfma16(fr1, ones, accZ[1]);
        }
    }

    __syncthreads();   // done with mask LDS; reuse as xchg

    // combine parity waves via LDS
    const int pr = wv >> 1;
    float* xb = xchg + (size_t)pr * (64 * 41) + (size_t)l * 41;
    if (par == 1) {
#pragma unroll
        for (int rt = 0; rt < 2; ++rt) {
#pragma unroll
            for (int nt = 0; nt < 4; ++nt)
#pragma unroll
                for (int r = 0; r < 4; ++r) xb[(rt * 4 + nt) * 4 + r] = accW[rt][nt][r];
#pragma unroll
            for (int r = 0; r < 4; ++r) xb[32 + rt * 4 + r] = accZ[rt][r];
        }
    }
    __syncthreads();
    if (par == 0) {
#pragma unroll
        for (int rt = 0; rt < 2; ++rt) {
            float zi[4];
#pragma unroll
            for (int r = 0; r < 4; ++r) zi[r] = 1.0f / (accZ[rt][r] + xb[32 + rt * 4 + r]);
#pragma unroll
            for (int nt = 0; nt < 4; ++nt) {
                const int col = head * 64 + nt * 16 + dlow;
                const float b = bias[col];
#pragma unroll
                for (int r = 0; r < 4; ++r) {
                    const int row = ibase + rt * 16 + q * 4 + r;
                    out[(size_t)row * GAT_C + col] =
                        (accW[rt][nt][r] + xb[(rt * 4 + nt) * 4 + r]) * zi[r] + b;
                }
            }
        }
    }
}

extern "C" void kernel_launch(void* const* d_in, const int* in_sizes, int n_in,
                              void* d_out, int out_size, void* d_ws, size_t ws_size,
                              hipStream_t stream) {
    const float* x    = (const float*)d_in[0];
    const int*   adj  = (const int*)d_in[1];
    const float* W    = (const float*)d_in[2];
    const float* asrc = (const float*)d_in[3];
    const float* adst = (const float*)d_in[4];
    const float* bias = (const float*)d_in[5];
    float* out = (float*)d_out;

    char* ws = (char*)d_ws;                     // needs ~6.4 MB
    _Float16* Hpack  = (_Float16*)ws;                          // 4 MB
    unsigned* maskw  = (unsigned*)(ws + (4u << 20));           // 2 MB
    float*    ddata  = (float*)(ws + (6u << 20));              // 256 KB
    float*    esrc   = (float*)(ws + (6u << 20) + (256u << 10));
    unsigned* dmax   = (unsigned*)(ws + (6u << 20) + (384u << 10));

    (void)hipMemsetAsync(dmax, 0, 8 * sizeof(unsigned), stream);
    hipLaunchKernelGGL(gat_prep, dim3(2560), dim3(256), 0, stream,
                       x, W, asrc, adst, adj, Hpack, ddata, esrc, dmax, maskw);
    hipLaunchKernelGGL(gat_attn, dim3(256), dim3(512), 0, stream,
                       maskw, Hpack, ddata, esrc, dmax, bias, out);
}

// Round 5
// 128.584 us; speedup vs baseline: 1.4341x; 1.4341x over previous
//
#include <hip/hip_runtime.h>
#include <hip/hip_bf16.h>
#include <hip/hip_fp16.h>

// DenseGAT fused kernel for MI355X.
// N=4096, IN=256, HEADS=8, D=64, C=512.
// logits are rank-1 per head + adjacency mask => no QK GEMM.
// Round 5: fix Hpack head stride (262144, was 524288 -> OOB garbage for
// heads 4-7). Otherwise identical to Round 4 design.
//
// ws layout:
//   Hpack : _Float16 [8][128][4][64][8] @ 0     (4 MB)   H in B-frag order
//   maskw : uint     [4096][128]        @ 4MB   (2 MB)   bit j&31 of word j>>5
//   ddata : float    [8][4096]          @ 6MB   (128 KB) e_dst*log2e
//   esrc  : float    [4096][8]          @ 6MB+128K (128 KB)
//   dmax  : uint     [8]                @ 6MB+256K

#define GAT_N 4096
#define GAT_K 256
#define GAT_C 512
#define GAT_H 8
#define L2E 1.4426950408889634f

typedef _Float16 v8h __attribute__((ext_vector_type(8)));
typedef float v4f __attribute__((ext_vector_type(4)));
typedef int v4i __attribute__((ext_vector_type(4)));

static __device__ inline v4f mfma16(v8h a, v8h b, v4f c) {
    return __builtin_amdgcn_mfma_f32_16x16x32_f16(a, b, c, 0, 0, 0);
}

// -------- Phase A: projection + e_src/e_dst + Hpack, PLUS bitmask build ------
// grid 2560: blocks 0..511 = proj (64 mtiles x 8 heads), 512..2559 = mask.
__global__ __launch_bounds__(256) void gat_prep(
    const float* __restrict__ x, const float* __restrict__ W,
    const float* __restrict__ asrc, const float* __restrict__ adst,
    const int* __restrict__ adj,
    _Float16* __restrict__ Hpack, float* __restrict__ ddata,
    float* __restrict__ esrc, unsigned* __restrict__ dmax,
    unsigned* __restrict__ maskw)
{
    const int bid = blockIdx.x;
    const int tid = threadIdx.x;

    if (bid >= 512) {
        // ---- ballot mask path: wave builds one u64 word per 64 elements ----
        const int g = (bid - 512) * 4 + (tid >> 6);     // wave 0..8191
        const int lane = tid & 63;
        const size_t base = (size_t)g * 2048;
        const int* pa = adj + base + lane;
        unsigned long long* mq = (unsigned long long*)maskw;
        const size_t wbase = base >> 6;
#pragma unroll 4
        for (int i = 0; i < 32; ++i) {
            int v = __builtin_nontemporal_load(pa + (size_t)i * 64);
            unsigned long long m = __ballot(v > 0);
            if (lane == 0) mq[wbase + i] = m;
        }
        return;
    }

    // ---- projection path ----
    const int head = bid & 7, mtile = bid >> 3;
    const int wv = tid >> 6, l = tid & 63;
    const int dlow = l & 15, q = l >> 4;
    const int rowbase = mtile * 64 + wv * 16;
    const int arow = rowbase + dlow;

    v4f acc[4] = {};
#pragma unroll
    for (int kc = 0; kc < 8; ++kc) {
        const int k0 = kc * 32 + q * 8;
        const float4* ap = (const float4*)(x + (size_t)arow * GAT_K + k0);
        float4 xa = ap[0], xb = ap[1];
        v8h af;
        af[0] = (_Float16)xa.x; af[1] = (_Float16)xa.y; af[2] = (_Float16)xa.z; af[3] = (_Float16)xa.w;
        af[4] = (_Float16)xb.x; af[5] = (_Float16)xb.y; af[6] = (_Float16)xb.z; af[7] = (_Float16)xb.w;
#pragma unroll
        for (int nt = 0; nt < 4; ++nt) {
            const int c = head * 64 + nt * 16 + dlow;
            const float4* bp = (const float4*)(W + (size_t)c * GAT_K + k0);
            float4 wa = bp[0], wb = bp[1];
            v8h bf;
            bf[0] = (_Float16)wa.x; bf[1] = (_Float16)wa.y; bf[2] = (_Float16)wa.z; bf[3] = (_Float16)wa.w;
            bf[4] = (_Float16)wb.x; bf[5] = (_Float16)wb.y; bf[6] = (_Float16)wb.z; bf[7] = (_Float16)wb.w;
            acc[nt] = mfma16(af, bf, acc[nt]);
        }
    }

    float as[4], ad[4];
#pragma unroll
    for (int nt = 0; nt < 4; ++nt) {
        const int d = nt * 16 + dlow;
        as[nt] = asrc[head * 64 + d];
        ad[nt] = adst[head * 64 + d];
    }
    float es[4], ed[4];
#pragma unroll
    for (int r = 0; r < 4; ++r) {
        float se = 0.f, de = 0.f;
#pragma unroll
        for (int nt = 0; nt < 4; ++nt) { se += acc[nt][r] * as[nt]; de += acc[nt][r] * ad[nt]; }
#pragma unroll
        for (int m = 1; m < 16; m <<= 1) { se += __shfl_xor(se, m); de += __shfl_xor(de, m); }
        es[r] = se; ed[r] = de;
    }
    if (dlow == 0) {
#pragma unroll
        for (int r = 0; r < 4; ++r) {
            const int j = rowbase + q * 4 + r;
            esrc[j * GAT_H + head] = es[r];
            ddata[(size_t)head * GAT_N + j] = ed[r] * L2E;
        }
        float mx = fmaxf(fmaxf(ed[0], ed[1]), fmaxf(ed[2], ed[3]));
        unsigned u = __float_as_uint(mx);
        unsigned enc = (u & 0x80000000u) ? ~u : (u | 0x80000000u);
        atomicMax(dmax + head, enc);
    }

    // Hpack: element (j, d) -> [head][j>>5][nt][(p>>3)*16 + dlow][p&7], p=j&31.
    const int jc = rowbase >> 5;
    const int p16 = rowbase & 16;
#pragma unroll
    for (int nt = 0; nt < 4; ++nt) {
#pragma unroll
        for (int rp = 0; rp < 4; rp += 2) {
            const int p = p16 + q * 4 + rp;
            const int qp = p >> 3, e = p & 7;
            const int lanep = qp * 16 + dlow;
            const size_t idx = ((((size_t)head * 128 + jc) * 4 + nt) * 64 + lanep) * 8 + e;
            union { unsigned u; _Float16 h[2]; } pk;
            pk.h[0] = (_Float16)acc[nt][rp];
            pk.h[1] = (_Float16)acc[nt][rp + 1];
            *(unsigned*)(Hpack + idx) = pk.u;
        }
    }
}

// ---------------- Phase B: fused mask + softmax + alpha@H -------------------
// grid 1024 = (it = bid>>3) x (head = bid&7  -> XCD-pinned), block 256 (4 waves).
// Wave par takes jc chunks with jc%4 == par; no barriers in the main loop;
// register double-buffered chunk pipeline (T14).
__global__ __launch_bounds__(256, 4) void gat_attn(
    const unsigned* __restrict__ maskw, const _Float16* __restrict__ Hpack,
    const float* __restrict__ ddata, const float* __restrict__ esrc,
    const unsigned* __restrict__ dmax, const float* __restrict__ bias,
    float* __restrict__ out)
{
    // mldsT[128][32] (16KB) unioned with xchg[3][64][41] (31488 B)
    __shared__ __align__(16) char smem[3 * 64 * 41 * 4];
    unsigned (*mldsT)[32] = (unsigned (*)[32])smem;
    float* xchg = (float*)smem;

    const int bid = blockIdx.x;
    const int head = bid & 7;
    const int it = bid >> 3;
    const int tid = threadIdx.x;
    const int wv = tid >> 6, l = tid & 63;
    const int par = wv;
    const int dlow = l & 15, q = l >> 4;
    const int qs = q * 8;
    const int ibase = it * 32;

    // stage 32-row mask transposed+swizzled: mldsT[w][r ^ (((w>>4)&3)<<3)]
    {
        const int r = tid >> 3, wb = (tid & 7) * 16;
        const int swz = (tid & 3) << 3;                 // == ((w>>4)&3)<<3 for w in [wb,wb+16)
        const int rs = r ^ swz;
        const v4i* mp = (const v4i*)(maskw + (size_t)(ibase + r) * 128 + wb);
#pragma unroll
        for (int k = 0; k < 4; ++k) {
            v4i a = mp[k];
            const int w0 = wb + k * 4;
            mldsT[w0 + 0][rs] = (unsigned)a.x;
            mldsT[w0 + 1][rs] = (unsigned)a.y;
            mldsT[w0 + 2][rs] = (unsigned)a.z;
            mldsT[w0 + 3][rs] = (unsigned)a.w;
        }
    }

    // per-row constants: a1 = (s-M)*log2e, a2 = (0.2s-M)*log2e, M = leaky(s+Dmax)
    const unsigned du = dmax[head];
    const float Dm = __uint_as_float((du & 0x80000000u) ? (du & 0x7fffffffu) : ~du);
    float a1[2], a2[2];
#pragma unroll
    for (int rt = 0; rt < 2; ++rt) {
        const int i = ibase + rt * 16 + dlow;
        const float s = esrc[i * GAT_H + head];
        const float sm = s + Dm;
        const float M = fmaxf(sm, 0.2f * sm);
        a1[rt] = (s - M) * L2E;
        a2[rt] = (0.2f * s - M) * L2E;
    }

    v4f accW[2][4] = {};
    v4f accZ[2] = {};
    v8h ones;
#pragma unroll
    for (int e = 0; e < 8; ++e) ones[e] = (_Float16)1.0f;

    const float* ddj = ddata + (size_t)head * GAT_N;
    const _Float16* Hl = Hpack + (size_t)head * 262144 + (size_t)l * 8;

    __syncthreads();   // mask visible; no barriers until epilogue

    // double-buffered chunk pipeline; wave handles jc = t*4 + par, t = 0..31
    unsigned Amw0, Amw1, Bmw0, Bmw1;
    float4 Ad0, Ad1, Bd0, Bd1;
    v8h Ah0, Ah1, Ah2, Ah3, Bh0, Bh1, Bh2, Bh3;

#define GAT_LOAD(P, T) {                                                     \
        const int jc_ = (T) * 4 + par;                                       \
        const int sw_ = ((jc_ >> 4) & 3) << 3;                               \
        P##mw0 = mldsT[jc_][dlow ^ sw_];                                     \
        P##mw1 = mldsT[jc_][(dlow + 16) ^ sw_];                              \
        const float4* dp_ = (const float4*)(ddj + (jc_ << 5) + qs);          \
        P##d0 = dp_[0]; P##d1 = dp_[1];                                      \
        const _Float16* hp_ = Hl + (size_t)jc_ * 2048;                       \
        P##h0 = *(const v8h*)(hp_);                                          \
        P##h1 = *(const v8h*)(hp_ + 512);                                    \
        P##h2 = *(const v8h*)(hp_ + 1024);                                   \
        P##h3 = *(const v8h*)(hp_ + 1536);                                   \
    }

#define GAT_E(E, D) {                                                        \
        const float dl_ = (D);                                               \
        float t0_ = fmaxf(dl_ + a1[0], __builtin_fmaf(dl_, 0.2f, a2[0]));    \
        float t1_ = fmaxf(dl_ + a1[1], __builtin_fmaf(dl_, 0.2f, a2[1]));    \
        t0_ = __builtin_amdgcn_exp2f(t0_) * (float)((b0_ >> (E)) & 1u);      \
        t1_ = __builtin_amdgcn_exp2f(t1_) * (float)((b1_ >> (E)) & 1u);      \
        fr0[E] = (_Float16)t0_; fr1[E] = (_Float16)t1_;                      \
    }

#define GAT_COMP(P) {                                                        \
        const unsigned b0_ = (P##mw0 >> qs) & 255u;                          \
        const unsigned b1_ = (P##mw1 >> qs) & 255u;                          \
        v8h fr0, fr1;                                                        \
        GAT_E(0, P##d0.x) GAT_E(1, P##d0.y) GAT_E(2, P##d0.z) GAT_E(3, P##d0.w) \
        GAT_E(4, P##d1.x) GAT_E(5, P##d1.y) GAT_E(6, P##d1.z) GAT_E(7, P##d1.w) \
        accW[0][0] = mfma16(fr0, P##h0, accW[0][0]);                         \
        accW[1][0] = mfma16(fr1, P##h0, accW[1][0]);                         \
        accW[0][1] = mfma16(fr0, P##h1, accW[0][1]);                         \
        accW[1][1] = mfma16(fr1, P##h1, accW[1][1]);                         \
        accW[0][2] = mfma16(fr0, P##h2, accW[0][2]);                         \
        accW[1][2] = mfma16(fr1, P##h2, accW[1][2]);                         \
        accW[0][3] = mfma16(fr0, P##h3, accW[0][3]);                         \
        accW[1][3] = mfma16(fr1, P##h3, accW[1][3]);                         \
        accZ[0] = mfma16(fr0, ones, accZ[0]);                                \
        accZ[1] = mfma16(fr1, ones, accZ[1]);                                \
    }

    GAT_LOAD(A, 0)
    for (int t = 0; t < 30; t += 2) {
        GAT_LOAD(B, t + 1)
        GAT_COMP(A)
        GAT_LOAD(A, t + 2)
        GAT_COMP(B)
    }
    GAT_LOAD(B, 31)
    GAT_COMP(A)
    GAT_COMP(B)
#undef GAT_LOAD
#undef GAT_E
#undef GAT_COMP

    __syncthreads();   // done with mask LDS; reuse as xchg

    // combine 4 waves: waves 1..3 write partials, wave 0 reduces + writes out
    if (wv != 0) {
        float* xb = xchg + (size_t)((wv - 1) * 64 + l) * 41;
#pragma unroll
        for (int rt = 0; rt < 2; ++rt) {
#pragma unroll
            for (int nt = 0; nt < 4; ++nt)
#pragma unroll
                for (int r = 0; r < 4; ++r) xb[(rt * 4 + nt) * 4 + r] = accW[rt][nt][r];
#pragma unroll
            for (int r = 0; r < 4; ++r) xb[32 + rt * 4 + r] = accZ[rt][r];
        }
    }
    __syncthreads();
    if (wv == 0) {
#pragma unroll
        for (int p = 0; p < 3; ++p) {
            const float* xr = xchg + (size_t)(p * 64 + l) * 41;
#pragma unroll
            for (int rt = 0; rt < 2; ++rt) {
#pragma unroll
                for (int nt = 0; nt < 4; ++nt)
#pragma unroll
                    for (int r = 0; r < 4; ++r) accW[rt][nt][r] += xr[(rt * 4 + nt) * 4 + r];
#pragma unroll
                for (int r = 0; r < 4; ++r) accZ[rt][r] += xr[32 + rt * 4 + r];
            }
        }
#pragma unroll
        for (int rt = 0; rt < 2; ++rt) {
            float zi[4];
#pragma unroll
            for (int r = 0; r < 4; ++r) zi[r] = 1.0f / accZ[rt][r];
#pragma unroll
            for (int nt = 0; nt < 4; ++nt) {
                const int col = head * 64 + nt * 16 + dlow;
                const float b = bias[col];
#pragma unroll
                for (int r = 0; r < 4; ++r) {
                    const int row = ibase + rt * 16 + q * 4 + r;
                    out[(size_t)row * GAT_C + col] = accW[rt][nt][r] * zi[r] + b;
                }
            }
        }
    }
}

extern "C" void kernel_launch(void* const* d_in, const int* in_sizes, int n_in,
                              void* d_out, int out_size, void* d_ws, size_t ws_size,
                              hipStream_t stream) {
    const float* x    = (const float*)d_in[0];
    const int*   adj  = (const int*)d_in[1];
    const float* W    = (const float*)d_in[2];
    const float* asrc = (const float*)d_in[3];
    const float* adst = (const float*)d_in[4];
    const float* bias = (const float*)d_in[5];
    float* out = (float*)d_out;

    char* ws = (char*)d_ws;                     // needs ~6.3 MB
    _Float16* Hpack  = (_Float16*)ws;                          // 4 MB
    unsigned* maskw  = (unsigned*)(ws + (4u << 20));           // 2 MB
    float*    ddata  = (float*)(ws + (6u << 20));              // 128 KB
    float*    esrc   = (float*)(ws + (6u << 20) + (128u << 10));
    unsigned* dmax   = (unsigned*)(ws + (6u << 20) + (256u << 10));

    (void)hipMemsetAsync(dmax, 0, 8 * sizeof(unsigned), stream);
    hipLaunchKernelGGL(gat_prep, dim3(2560), dim3(256), 0, stream,
                       x, W, asrc, adst, adj, Hpack, ddata, esrc, dmax, maskw);
    hipLaunchKernelGGL(gat_attn, dim3(1024), dim3(256), 0, stream,
                       maskw, Hpack, ddata, esrc, dmax, bias, out);
}

// Round 6
// 117.506 us; speedup vs baseline: 1.5693x; 1.0943x over previous
//
#include <hip/hip_runtime.h>
#include <hip/hip_bf16.h>
#include <hip/hip_fp16.h>

// DenseGAT fused kernel for MI355X.
// N=4096, IN=256, HEADS=8, D=64, C=512.
// logits are rank-1 per head + adjacency mask => no QK GEMM.
// Round 6: (a) mask builder rewritten to int4-coalesced loads + nibble
// shfl-OR combine (was dword-per-lane ballot, 768 GB/s latency-bound);
// (b) attn uses 16-row i-tiles, grid 2048, for ~20 resident waves/CU.
//
// ws layout:
//   Hpack : _Float16 [8][128][4][64][8] @ 0     (4 MB)   H in B-frag order
//   maskw : uint     [4096][128]        @ 4MB   (2 MB)   bit j&31 of word j>>5
//   ddata : float    [8][4096]          @ 6MB   (128 KB) e_dst*log2e
//   esrc  : float    [4096][8]          @ 6MB+128K (128 KB)
//   dmax  : uint     [8]                @ 6MB+256K

#define GAT_N 4096
#define GAT_K 256
#define GAT_C 512
#define GAT_H 8
#define L2E 1.4426950408889634f

typedef _Float16 v8h __attribute__((ext_vector_type(8)));
typedef float v4f __attribute__((ext_vector_type(4)));
typedef int v4i __attribute__((ext_vector_type(4)));

static __device__ inline v4f mfma16(v8h a, v8h b, v4f c) {
    return __builtin_amdgcn_mfma_f32_16x16x32_f16(a, b, c, 0, 0, 0);
}

// -------- Phase A: projection + e_src/e_dst + Hpack, PLUS bitmask build ------
// grid 2560: blocks 0..511 = proj (64 mtiles x 8 heads), 512..2559 = mask.
__global__ __launch_bounds__(256) void gat_prep(
    const float* __restrict__ x, const float* __restrict__ W,
    const float* __restrict__ asrc, const float* __restrict__ adst,
    const int* __restrict__ adj,
    _Float16* __restrict__ Hpack, float* __restrict__ ddata,
    float* __restrict__ esrc, unsigned* __restrict__ dmax,
    unsigned* __restrict__ maskw)
{
    const int bid = blockIdx.x;
    const int tid = threadIdx.x;

    if (bid >= 512) {
        // ---- mask path: wave covers 2048 ints in 8 iters of 256 (1KB/inst).
        // lane loads int4 -> 4-bit nibble at bit (lane&7)*4; OR-combine across
        // 8-lane groups via shfl_xor; group leader stores one u32 word.
        const int g = (bid - 512) * 4 + (tid >> 6);     // wave 0..8191
        const int lane = tid & 63;
        const size_t base = (size_t)g * 2048;           // flat int index
        const int* pa = adj + base + (size_t)lane * 4;
        const int sh = (lane & 7) * 4;
        const int wofs = lane >> 3;                     // 0..7
        unsigned* mw = maskw + (base >> 5);
#pragma unroll
        for (int i = 0; i < 8; ++i) {
            v4i v = __builtin_nontemporal_load((const v4i*)(pa + i * 256));
            unsigned nib = (unsigned)(v.x > 0) | ((unsigned)(v.y > 0) << 1)
                         | ((unsigned)(v.z > 0) << 2) | ((unsigned)(v.w > 0) << 3);
            unsigned w = nib << sh;
            w |= __shfl_xor(w, 1);
            w |= __shfl_xor(w, 2);
            w |= __shfl_xor(w, 4);
            if ((lane & 7) == 0) mw[i * 8 + wofs] = w;
        }
        return;
    }

    // ---- projection path ----
    const int head = bid & 7, mtile = bid >> 3;
    const int wv = tid >> 6, l = tid & 63;
    const int dlow = l & 15, q = l >> 4;
    const int rowbase = mtile * 64 + wv * 16;
    const int arow = rowbase + dlow;

    v4f acc[4] = {};
#pragma unroll
    for (int kc = 0; kc < 8; ++kc) {
        const int k0 = kc * 32 + q * 8;
        const float4* ap = (const float4*)(x + (size_t)arow * GAT_K + k0);
        float4 xa = ap[0], xb = ap[1];
        v8h af;
        af[0] = (_Float16)xa.x; af[1] = (_Float16)xa.y; af[2] = (_Float16)xa.z; af[3] = (_Float16)xa.w;
        af[4] = (_Float16)xb.x; af[5] = (_Float16)xb.y; af[6] = (_Float16)xb.z; af[7] = (_Float16)xb.w;
#pragma unroll
        for (int nt = 0; nt < 4; ++nt) {
            const int c = head * 64 + nt * 16 + dlow;
            const float4* bp = (const float4*)(W + (size_t)c * GAT_K + k0);
            float4 wa = bp[0], wb = bp[1];
            v8h bf;
            bf[0] = (_Float16)wa.x; bf[1] = (_Float16)wa.y; bf[2] = (_Float16)wa.z; bf[3] = (_Float16)wa.w;
            bf[4] = (_Float16)wb.x; bf[5] = (_Float16)wb.y; bf[6] = (_Float16)wb.z; bf[7] = (_Float16)wb.w;
            acc[nt] = mfma16(af, bf, acc[nt]);
        }
    }

    float as[4], ad[4];
#pragma unroll
    for (int nt = 0; nt < 4; ++nt) {
        const int d = nt * 16 + dlow;
        as[nt] = asrc[head * 64 + d];
        ad[nt] = adst[head * 64 + d];
    }
    float es[4], ed[4];
#pragma unroll
    for (int r = 0; r < 4; ++r) {
        float se = 0.f, de = 0.f;
#pragma unroll
        for (int nt = 0; nt < 4; ++nt) { se += acc[nt][r] * as[nt]; de += acc[nt][r] * ad[nt]; }
#pragma unroll
        for (int m = 1; m < 16; m <<= 1) { se += __shfl_xor(se, m); de += __shfl_xor(de, m); }
        es[r] = se; ed[r] = de;
    }
    if (dlow == 0) {
#pragma unroll
        for (int r = 0; r < 4; ++r) {
            const int j = rowbase + q * 4 + r;
            esrc[j * GAT_H + head] = es[r];
            ddata[(size_t)head * GAT_N + j] = ed[r] * L2E;
        }
        float mx = fmaxf(fmaxf(ed[0], ed[1]), fmaxf(ed[2], ed[3]));
        unsigned u = __float_as_uint(mx);
        unsigned enc = (u & 0x80000000u) ? ~u : (u | 0x80000000u);
        atomicMax(dmax + head, enc);
    }

    // Hpack: element (j, d) -> [head][j>>5][nt][(p>>3)*16 + dlow][p&7], p=j&31.
    const int jc = rowbase >> 5;
    const int p16 = rowbase & 16;
#pragma unroll
    for (int nt = 0; nt < 4; ++nt) {
#pragma unroll
        for (int rp = 0; rp < 4; rp += 2) {
            const int p = p16 + q * 4 + rp;
            const int qp = p >> 3, e = p & 7;
            const int lanep = qp * 16 + dlow;
            const size_t idx = ((((size_t)head * 128 + jc) * 4 + nt) * 64 + lanep) * 8 + e;
            union { unsigned u; _Float16 h[2]; } pk;
            pk.h[0] = (_Float16)acc[nt][rp];
            pk.h[1] = (_Float16)acc[nt][rp + 1];
            *(unsigned*)(Hpack + idx) = pk.u;
        }
    }
}

// ---------------- Phase B: fused mask + softmax + alpha@H -------------------
// grid 2048 = (it = bid>>3, 16 rows) x (head = bid&7 -> XCD-pinned).
// block 256 (4 waves); wave par takes jc chunks with jc%4 == par;
// no barriers in the main loop; register double-buffered chunk pipeline.
__global__ __launch_bounds__(256, 5) void gat_attn(
    const unsigned* __restrict__ maskw, const _Float16* __restrict__ Hpack,
    const float* __restrict__ ddata, const float* __restrict__ esrc,
    const unsigned* __restrict__ dmax, const float* __restrict__ bias,
    float* __restrict__ out)
{
    // mldsT[128][16] u32 (8KB) unioned with xchg[3][64][21] f32 (16128 B)
    __shared__ __align__(16) char smem[3 * 64 * 21 * 4];
    unsigned (*mldsT)[16] = (unsigned (*)[16])smem;
    float* xchg = (float*)smem;

    const int bid = blockIdx.x;
    const int head = bid & 7;
    const int it = bid >> 3;
    const int tid = threadIdx.x;
    const int wv = tid >> 6, l = tid & 63;
    const int par = wv;
    const int dlow = l & 15, q = l >> 4;
    const int qs = q * 8;
    const int ibase = it * 16;

    // stage 16-row mask transposed+swizzled: word w row r at mldsT[w][r ^ ((w>>3)&15)]
    {
        const int r = tid >> 4, t15 = tid & 15;
        const int wb = t15 * 8;
        const int rs = r ^ t15;                        // (w>>3)&15 == t15 for w in [wb,wb+8)
        const v4i* mp = (const v4i*)(maskw + (size_t)(ibase + r) * 128 + wb);
        v4i a = mp[0], b = mp[1];
        mldsT[wb + 0][rs] = (unsigned)a.x; mldsT[wb + 1][rs] = (unsigned)a.y;
        mldsT[wb + 2][rs] = (unsigned)a.z; mldsT[wb + 3][rs] = (unsigned)a.w;
        mldsT[wb + 4][rs] = (unsigned)b.x; mldsT[wb + 5][rs] = (unsigned)b.y;
        mldsT[wb + 6][rs] = (unsigned)b.z; mldsT[wb + 7][rs] = (unsigned)b.w;
    }

    // per-row constants: a1 = (s-M)*log2e, a2 = (0.2s-M)*log2e, M = leaky(s+Dmax)
    const unsigned du = dmax[head];
    const float Dm = __uint_as_float((du & 0x80000000u) ? (du & 0x7fffffffu) : ~du);
    float a1, a2;
    {
        const int i = ibase + dlow;
        const float s = esrc[i * GAT_H + head];
        const float sm = s + Dm;
        const float M = fmaxf(sm, 0.2f * sm);
        a1 = (s - M) * L2E;
        a2 = (0.2f * s - M) * L2E;
    }

    v4f accW[4] = {};
    v4f accZ = {};
    v8h ones;
#pragma unroll
    for (int e = 0; e < 8; ++e) ones[e] = (_Float16)1.0f;

    const float* ddj = ddata + (size_t)head * GAT_N;
    const _Float16* Hl = Hpack + (size_t)head * 262144 + (size_t)l * 8;

    __syncthreads();   // mask visible; no barriers until epilogue

    // double-buffered chunk pipeline; wave handles jc = t*4 + par, t = 0..31
    unsigned Amw, Bmw;
    float4 Ad0, Ad1, Bd0, Bd1;
    v8h Ah0, Ah1, Ah2, Ah3, Bh0, Bh1, Bh2, Bh3;

#define GAT_LOAD(P, T) {                                                     \
        const int jc_ = (T) * 4 + par;                                       \
        P##mw = mldsT[jc_][dlow ^ ((jc_ >> 3) & 15)];                        \
        const float4* dp_ = (const float4*)(ddj + (jc_ << 5) + qs);          \
        P##d0 = dp_[0]; P##d1 = dp_[1];                                      \
        const _Float16* hp_ = Hl + (size_t)jc_ * 2048;                       \
        P##h0 = *(const v8h*)(hp_);                                          \
        P##h1 = *(const v8h*)(hp_ + 512);                                    \
        P##h2 = *(const v8h*)(hp_ + 1024);                                   \
        P##h3 = *(const v8h*)(hp_ + 1536);                                   \
    }

#define GAT_E(E, D) {                                                        \
        const float dl_ = (D);                                               \
        float t0_ = fmaxf(dl_ + a1, __builtin_fmaf(dl_, 0.2f, a2));          \
        t0_ = __builtin_amdgcn_exp2f(t0_) * (float)((b_ >> (E)) & 1u);       \
        fr[E] = (_Float16)t0_;                                               \
    }

#define GAT_COMP(P) {                                                        \
        const unsigned b_ = (P##mw >> qs) & 255u;                            \
        v8h fr;                                                              \
        GAT_E(0, P##d0.x) GAT_E(1, P##d0.y) GAT_E(2, P##d0.z) GAT_E(3, P##d0.w) \
        GAT_E(4, P##d1.x) GAT_E(5, P##d1.y) GAT_E(6, P##d1.z) GAT_E(7, P##d1.w) \
        accW[0] = mfma16(fr, P##h0, accW[0]);                                \
        accW[1] = mfma16(fr, P##h1, accW[1]);                                \
        accW[2] = mfma16(fr, P##h2, accW[2]);                                \
        accW[3] = mfma16(fr, P##h3, accW[3]);                                \
        accZ    = mfma16(fr, ones,  accZ);                                   \
    }

    GAT_LOAD(A, 0)
    for (int t = 0; t < 30; t += 2) {
        GAT_LOAD(B, t + 1)
        GAT_COMP(A)
        GAT_LOAD(A, t + 2)
        GAT_COMP(B)
    }
    GAT_LOAD(B, 31)
    GAT_COMP(A)
    GAT_COMP(B)
#undef GAT_LOAD
#undef GAT_E
#undef GAT_COMP

    __syncthreads();   // done with mask LDS; reuse as xchg

    // combine 4 waves: waves 1..3 write partials, wave 0 reduces + writes out
    if (wv != 0) {
        float* xb = xchg + (size_t)((wv - 1) * 64 + l) * 21;
#pragma unroll
        for (int nt = 0; nt < 4; ++nt)
#pragma unroll
            for (int r = 0; r < 4; ++r) xb[nt * 4 + r] = accW[nt][r];
#pragma unroll
        for (int r = 0; r < 4; ++r) xb[16 + r] = accZ[r];
    }
    __syncthreads();
    if (wv == 0) {
#pragma unroll
        for (int p = 0; p < 3; ++p) {
            const float* xr = xchg + (size_t)(p * 64 + l) * 21;
#pragma unroll
            for (int nt = 0; nt < 4; ++nt)
#pragma unroll
                for (int r = 0; r < 4; ++r) accW[nt][r] += xr[nt * 4 + r];
#pragma unroll
            for (int r = 0; r < 4; ++r) accZ[r] += xr[16 + r];
        }
        float zi[4];
#pragma unroll
        for (int r = 0; r < 4; ++r) zi[r] = 1.0f / accZ[r];
#pragma unroll
        for (int nt = 0; nt < 4; ++nt) {
            const int col = head * 64 + nt * 16 + dlow;
            const float b = bias[col];
#pragma unroll
            for (int r = 0; r < 4; ++r) {
                const int row = ibase + q * 4 + r;
                out[(size_t)row * GAT_C + col] = accW[nt][r] * zi[r] + b;
            }
        }
    }
}

extern "C" void kernel_launch(void* const* d_in, const int* in_sizes, int n_in,
                              void* d_out, int out_size, void* d_ws, size_t ws_size,
                              hipStream_t stream) {
    const float* x    = (const float*)d_in[0];
    const int*   adj  = (const int*)d_in[1];
    const float* W    = (const float*)d_in[2];
    const float* asrc = (const float*)d_in[3];
    const float* adst = (const float*)d_in[4];
    const float* bias = (const float*)d_in[5];
    float* out = (float*)d_out;

    char* ws = (char*)d_ws;                     // needs ~6.3 MB
    _Float16* Hpack  = (_Float16*)ws;                          // 4 MB
    unsigned* maskw  = (unsigned*)(ws + (4u << 20));           // 2 MB
    float*    ddata  = (float*)(ws + (6u << 20));              // 128 KB
    float*    esrc   = (float*)(ws + (6u << 20) + (128u << 10));
    unsigned* dmax   = (unsigned*)(ws + (6u << 20) + (256u << 10));

    (void)hipMemsetAsync(dmax, 0, 8 * sizeof(unsigned), stream);
    hipLaunchKernelGGL(gat_prep, dim3(2560), dim3(256), 0, stream,
                       x, W, asrc, adst, adj, Hpack, ddata, esrc, dmax, maskw);
    hipLaunchKernelGGL(gat_attn, dim3(2048), dim3(256), 0, stream,
                       maskw, Hpack, ddata, esrc, dmax, bias, out);
}

// Round 8
// 108.901 us; speedup vs baseline: 1.6933x; 1.0790x over previous
//
#include <hip/hip_runtime.h>
#include <hip/hip_bf16.h>
#include <hip/hip_fp16.h>

// DenseGAT fused kernel for MI355X.
// N=4096, IN=256, HEADS=8, D=64, C=512.
// Round 8: fix R7's mask byte-smear carry bug (mask to 4 bits before the
// 0x204081 multiply; 8-bit input overlapped across 7-bit strides and
// carried into kept bit positions, corrupting masks when b0&b7 set).
//
// ws layout:
//   Hpack : _Float16 [8][128][4][64][8] @ 0        (4 MB)  H in B-frag order
//   maskw : uint     [4096][128]        @ 4M       (2 MB)  bit j&31 of word j>>5
//   ddata : float    [8][4096]          @ 6M       (128 KB) e_dst*log2e
//   esrc  : float    [4096][8]          @ 6M+128K  (128 KB)
//   Epk1  : uint     [8][4096]          @ 6M+256K  (128 KB) {E1,E1} f16x2
//   Epk2  : uint     [8][4096]          @ 6M+384K  (128 KB)
//   F1    : _Float16 [8][4096]          @ 6M+512K  (64 KB)
//   F2    : _Float16 [8][4096]          @ 6M+576K  (64 KB)
//   dmax  : uint     [8]                @ 6M+640K

#define GAT_N 4096
#define GAT_K 256
#define GAT_C 512
#define GAT_H 8
#define L2E 1.4426950408889634f

typedef _Float16 v8h __attribute__((ext_vector_type(8)));
typedef _Float16 f16x2 __attribute__((ext_vector_type(2)));
typedef float v4f __attribute__((ext_vector_type(4)));
typedef int v4i __attribute__((ext_vector_type(4)));

union U8 { v4i w; v8h h; };

static __device__ inline v4f mfma16(v8h a, v8h b, v4f c) {
    return __builtin_amdgcn_mfma_f32_16x16x32_f16(a, b, c, 0, 0, 0);
}

static __device__ inline unsigned pmax2(f16x2 e1, f16x2 e2, int f1w, int f2w) {
    f16x2 f1 = __builtin_bit_cast(f16x2, f1w);
    f16x2 f2 = __builtin_bit_cast(f16x2, f2w);
    f16x2 p1 = e1 * f1;
    f16x2 p2 = e2 * f2;
    f16x2 mx = __builtin_elementwise_max(p1, p2);
    return __builtin_bit_cast(unsigned, mx);
}

static __device__ inline float dmax_decode(unsigned du) {
    return __uint_as_float((du & 0x80000000u) ? (du & 0x7fffffffu) : ~du);
}

// -------- Phase A: projection + e_src/e_dst + Hpack, PLUS bitmask build ------
// grid 2560: blocks 0..511 = proj (64 mtiles x 8 heads), 512..2559 = mask.
__global__ __launch_bounds__(256) void gat_prep(
    const float* __restrict__ x, const float* __restrict__ W,
    const float* __restrict__ asrc, const float* __restrict__ adst,
    const int* __restrict__ adj,
    _Float16* __restrict__ Hpack, float* __restrict__ ddata,
    float* __restrict__ esrc, unsigned* __restrict__ dmax,
    unsigned* __restrict__ maskw)
{
    const int bid = blockIdx.x;
    const int tid = threadIdx.x;

    if (bid >= 512) {
        // ---- mask path: lane covers 8 consecutive ints per iter; ALL loads
        // issued before any shfl (8 KB in flight per wave).
        const int g = (bid - 512) * 4 + (tid >> 6);     // wave 0..8191
        const int lane = tid & 63;
        const size_t base = (size_t)g * 2048;           // flat int index
        const int* pa = adj + base + (size_t)lane * 8;
        v4i v[8];
#pragma unroll
        for (int i = 0; i < 4; ++i) {
            v[2 * i]     = __builtin_nontemporal_load((const v4i*)(pa + (size_t)i * 512));
            v[2 * i + 1] = __builtin_nontemporal_load((const v4i*)(pa + (size_t)i * 512 + 4));
        }
#pragma unroll
        for (int i = 0; i < 4; ++i) {
            v4i a = v[2 * i], b = v[2 * i + 1];
            unsigned bits = (unsigned)(a.x > 0)        | ((unsigned)(a.y > 0) << 1)
                          | ((unsigned)(a.z > 0) << 2) | ((unsigned)(a.w > 0) << 3)
                          | ((unsigned)(b.x > 0) << 4) | ((unsigned)(b.y > 0) << 5)
                          | ((unsigned)(b.z > 0) << 6) | ((unsigned)(b.w > 0) << 7);
            unsigned w = bits << ((lane & 3) * 8);
            w |= __shfl_xor(w, 1);
            w |= __shfl_xor(w, 2);
            if ((lane & 3) == 0) maskw[(base >> 5) + i * 16 + (lane >> 2)] = w;
        }
        return;
    }

    // ---- projection path ----
    const int head = bid & 7, mtile = bid >> 3;
    const int wv = tid >> 6, l = tid & 63;
    const int dlow = l & 15, q = l >> 4;
    const int rowbase = mtile * 64 + wv * 16;
    const int arow = rowbase + dlow;

    v4f acc[4] = {};
#pragma unroll
    for (int kc = 0; kc < 8; ++kc) {
        const int k0 = kc * 32 + q * 8;
        const float4* ap = (const float4*)(x + (size_t)arow * GAT_K + k0);
        float4 xa = ap[0], xb = ap[1];
        v8h af;
        af[0] = (_Float16)xa.x; af[1] = (_Float16)xa.y; af[2] = (_Float16)xa.z; af[3] = (_Float16)xa.w;
        af[4] = (_Float16)xb.x; af[5] = (_Float16)xb.y; af[6] = (_Float16)xb.z; af[7] = (_Float16)xb.w;
#pragma unroll
        for (int nt = 0; nt < 4; ++nt) {
            const int c = head * 64 + nt * 16 + dlow;
            const float4* bp = (const float4*)(W + (size_t)c * GAT_K + k0);
            float4 wa = bp[0], wb = bp[1];
            v8h bf;
            bf[0] = (_Float16)wa.x; bf[1] = (_Float16)wa.y; bf[2] = (_Float16)wa.z; bf[3] = (_Float16)wa.w;
            bf[4] = (_Float16)wb.x; bf[5] = (_Float16)wb.y; bf[6] = (_Float16)wb.z; bf[7] = (_Float16)wb.w;
            acc[nt] = mfma16(af, bf, acc[nt]);
        }
    }

    float as[4], ad[4];
#pragma unroll
    for (int nt = 0; nt < 4; ++nt) {
        const int d = nt * 16 + dlow;
        as[nt] = asrc[head * 64 + d];
        ad[nt] = adst[head * 64 + d];
    }
    float es[4], ed[4];
#pragma unroll
    for (int r = 0; r < 4; ++r) {
        float se = 0.f, de = 0.f;
#pragma unroll
        for (int nt = 0; nt < 4; ++nt) { se += acc[nt][r] * as[nt]; de += acc[nt][r] * ad[nt]; }
#pragma unroll
        for (int m = 1; m < 16; m <<= 1) { se += __shfl_xor(se, m); de += __shfl_xor(de, m); }
        es[r] = se; ed[r] = de;
    }
    if (dlow == 0) {
#pragma unroll
        for (int r = 0; r < 4; ++r) {
            const int j = rowbase + q * 4 + r;
            esrc[j * GAT_H + head] = es[r];
            ddata[(size_t)head * GAT_N + j] = ed[r] * L2E;
        }
        float mx = fmaxf(fmaxf(ed[0], ed[1]), fmaxf(ed[2], ed[3]));
        unsigned u = __float_as_uint(mx);
        unsigned enc = (u & 0x80000000u) ? ~u : (u | 0x80000000u);
        atomicMax(dmax + head, enc);
    }

    // Hpack: element (j, d) -> [head][j>>5][nt][(p>>3)*16 + dlow][p&7], p=j&31.
    const int jc = rowbase >> 5;
    const int p16 = rowbase & 16;
#pragma unroll
    for (int nt = 0; nt < 4; ++nt) {
#pragma unroll
        for (int rp = 0; rp < 4; rp += 2) {
            const int p = p16 + q * 4 + rp;
            const int qp = p >> 3, e = p & 7;
            const int lanep = qp * 16 + dlow;
            const size_t idx = ((((size_t)head * 128 + jc) * 4 + nt) * 64 + lanep) * 8 + e;
            union { unsigned u; _Float16 h[2]; } pk;
            pk.h[0] = (_Float16)acc[nt][rp];
            pk.h[1] = (_Float16)acc[nt][rp + 1];
            *(unsigned*)(Hpack + idx) = pk.u;
        }
    }
}

// -------- Phase A2: per-i and per-j exponential factor tables ---------------
// E1 = exp(s+Dm-M), E2 = exp(0.2s+0.2Dm-M), M = leaky(s+Dm)  (per head,i)
// F1 = exp(d-Dm),   F2 = exp(0.2(d-Dm))                       (per head,j)
// All <= 1. grid 128 x 256.
__global__ __launch_bounds__(256) void gat_ftab(
    const float* __restrict__ esrc, const float* __restrict__ ddata,
    const unsigned* __restrict__ dmax,
    unsigned* __restrict__ Epk1, unsigned* __restrict__ Epk2,
    _Float16* __restrict__ F1, _Float16* __restrict__ F2)
{
    const int idx = blockIdx.x * 256 + threadIdx.x;   // head*4096 + i
    const int head = idx >> 12, i = idx & 4095;
    const float Dm = dmax_decode(dmax[head]);
    const float s = esrc[i * GAT_H + head];
    const float sm = s + Dm;
    const float M = fmaxf(sm, 0.2f * sm);
    const float e1 = __builtin_amdgcn_exp2f((sm - M) * L2E);
    const float e2 = __builtin_amdgcn_exp2f((0.2f * sm - M) * L2E);
    union { _Float16 h[2]; unsigned u; } pk;
    pk.h[0] = (_Float16)e1; pk.h[1] = (_Float16)e1; Epk1[idx] = pk.u;
    pk.h[0] = (_Float16)e2; pk.h[1] = (_Float16)e2; Epk2[idx] = pk.u;
    const float dl = ddata[idx] - Dm * L2E;           // (d - Dm)*log2e
    F1[idx] = (_Float16)__builtin_amdgcn_exp2f(dl);
    F2[idx] = (_Float16)__builtin_amdgcn_exp2f(0.2f * dl);
}

// ---------------- Phase B: fused mask + softmax + alpha@H -------------------
// grid 1024 = (it = bid>>3, 32 rows) x (head = bid&7 -> XCD-pinned).
// block 256 (4 waves): wave wv -> i-half = wv>>1 (16 rows), parity = wv&1
// (jc chunks with jc%2==par). No barriers in main loop; reg double-buffer.
__global__ __launch_bounds__(256, 4) void gat_attn(
    const unsigned* __restrict__ maskw, const _Float16* __restrict__ Hpack,
    const unsigned* __restrict__ Epk1, const unsigned* __restrict__ Epk2,
    const _Float16* __restrict__ F1, const _Float16* __restrict__ F2,
    const float* __restrict__ bias, float* __restrict__ out)
{
    __shared__ __align__(16) unsigned mlds[128][33];  // ~16.9 KB, pad kills conflicts
    __shared__ __align__(16) float xchg[2][64][21];   // ~10.8 KB

    const int bid = blockIdx.x;
    const int head = bid & 7;
    const int it = bid >> 3;
    const int tid = threadIdx.x;
    const int wv = tid >> 6, l = tid & 63;
    const int half = wv >> 1, par = wv & 1;
    const int dlow = l & 15, q = l >> 4, qs = q * 8;
    const int ibase = it * 32;
    const int mrow = half * 16 + dlow;
    const int irow = ibase + mrow;

    // stage 32-row mask: mlds[w][r]
    {
        const int r = tid >> 3, wb = (tid & 7) * 16;
        const unsigned* mp = maskw + (size_t)(ibase + r) * 128 + wb;
#pragma unroll
        for (int k = 0; k < 4; ++k) {
            v4i a = *(const v4i*)(mp + k * 4);
            mlds[wb + k * 4 + 0][r] = (unsigned)a.x;
            mlds[wb + k * 4 + 1][r] = (unsigned)a.y;
            mlds[wb + k * 4 + 2][r] = (unsigned)a.z;
            mlds[wb + k * 4 + 3][r] = (unsigned)a.w;
        }
    }

    const f16x2 E1p = __builtin_bit_cast(f16x2, Epk1[head * GAT_N + irow]);
    const f16x2 E2p = __builtin_bit_cast(f16x2, Epk2[head * GAT_N + irow]);

    v4f accW[4] = {};
    v4f accZ = {};
    v8h ones;
#pragma unroll
    for (int e = 0; e < 8; ++e) ones[e] = (_Float16)1.0f;

    const _Float16* Hl = Hpack + (size_t)head * 262144 + (size_t)l * 8;
    const _Float16* F1h = F1 + head * GAT_N;
    const _Float16* F2h = F2 + head * GAT_N;

    __syncthreads();   // mask visible; no barriers until epilogue

    unsigned Amw, Bmw;
    v4i Af1, Af2, Bf1, Bf2;
    v8h Ah0, Ah1, Ah2, Ah3, Bh0, Bh1, Bh2, Bh3;

#define GAT_LOAD(P, T) {                                                     \
        const int jc_ = (T) * 2 + par;                                       \
        P##mw = mlds[jc_][mrow];                                             \
        const int kg_ = (jc_ << 5) + qs;                                     \
        P##f1 = *(const v4i*)(F1h + kg_);                                    \
        P##f2 = *(const v4i*)(F2h + kg_);                                    \
        const _Float16* hp_ = Hl + (size_t)jc_ * 2048;                       \
        P##h0 = *(const v8h*)(hp_);                                          \
        P##h1 = *(const v8h*)(hp_ + 512);                                    \
        P##h2 = *(const v8h*)(hp_ + 1024);                                   \
        P##h3 = *(const v8h*)(hp_ + 1536);                                   \
    }

    // byte-smear: 4-bit fields only (4-bit copies at 7-bit stride never carry;
    // the R7 bug was smearing the full 8-bit field).
#define GAT_COMP(P) {                                                        \
        const unsigned b8_ = (P##mw >> qs) & 255u;                           \
        const unsigned z1_ = (((b8_ & 15u) * 0x204081u) << 7) & 0x80808080u; \
        const unsigned z2_ = (((b8_ >> 4) * 0x204081u) << 7) & 0x80808080u;  \
        const unsigned m1_ = (z1_ >> 7) * 255u;   /* bytes FF/00 = bits0-3 */\
        const unsigned m2_ = (z2_ >> 7) * 255u;   /* bytes FF/00 = bits4-7 */\
        const unsigned M0_ = __builtin_amdgcn_perm(0u, m1_, 0x01010000u);    \
        const unsigned M1_ = __builtin_amdgcn_perm(0u, m1_, 0x03030202u);    \
        const unsigned M2_ = __builtin_amdgcn_perm(0u, m2_, 0x01010000u);    \
        const unsigned M3_ = __builtin_amdgcn_perm(0u, m2_, 0x03030202u);    \
        U8 fr_;                                                              \
        fr_.w[0] = (int)(pmax2(E1p, E2p, P##f1[0], P##f2[0]) & M0_);         \
        fr_.w[1] = (int)(pmax2(E1p, E2p, P##f1[1], P##f2[1]) & M1_);         \
        fr_.w[2] = (int)(pmax2(E1p, E2p, P##f1[2], P##f2[2]) & M2_);         \
        fr_.w[3] = (int)(pmax2(E1p, E2p, P##f1[3], P##f2[3]) & M3_);         \
        accW[0] = mfma16(fr_.h, P##h0, accW[0]);                             \
        accW[1] = mfma16(fr_.h, P##h1, accW[1]);                             \
        accW[2] = mfma16(fr_.h, P##h2, accW[2]);                             \
        accW[3] = mfma16(fr_.h, P##h3, accW[3]);                             \
        accZ    = mfma16(fr_.h, ones,  accZ);                                \
    }

    GAT_LOAD(A, 0)
    for (int t = 0; t < 62; t += 2) {
        GAT_LOAD(B, t + 1)
        GAT_COMP(A)
        GAT_LOAD(A, t + 2)
        GAT_COMP(B)
    }
    GAT_LOAD(B, 63)
    GAT_COMP(A)
    GAT_COMP(B)
#undef GAT_LOAD
#undef GAT_COMP

    __syncthreads();

    // combine parity waves per half: par==1 writes, par==0 reduces + outputs
    if (par == 1) {
        float* xb = &xchg[half][l][0];
#pragma unroll
        for (int nt = 0; nt < 4; ++nt)
#pragma unroll
            for (int r = 0; r < 4; ++r) xb[nt * 4 + r] = accW[nt][r];
#pragma unroll
        for (int r = 0; r < 4; ++r) xb[16 + r] = accZ[r];
    }
    __syncthreads();
    if (par == 0) {
        const float* xr = &xchg[half][l][0];
#pragma unroll
        for (int nt = 0; nt < 4; ++nt)
#pragma unroll
            for (int r = 0; r < 4; ++r) accW[nt][r] += xr[nt * 4 + r];
#pragma unroll
        for (int r = 0; r < 4; ++r) accZ[r] += xr[16 + r];
        float zi[4];
#pragma unroll
        for (int r = 0; r < 4; ++r) zi[r] = 1.0f / accZ[r];
#pragma unroll
        for (int nt = 0; nt < 4; ++nt) {
            const int col = head * 64 + nt * 16 + dlow;
            const float b = bias[col];
#pragma unroll
            for (int r = 0; r < 4; ++r) {
                const int row = ibase + half * 16 + q * 4 + r;
                out[(size_t)row * GAT_C + col] = accW[nt][r] * zi[r] + b;
            }
        }
    }
}

extern "C" void kernel_launch(void* const* d_in, const int* in_sizes, int n_in,
                              void* d_out, int out_size, void* d_ws, size_t ws_size,
                              hipStream_t stream) {
    const float* x    = (const float*)d_in[0];
    const int*   adj  = (const int*)d_in[1];
    const float* W    = (const float*)d_in[2];
    const float* asrc = (const float*)d_in[3];
    const float* adst = (const float*)d_in[4];
    const float* bias = (const float*)d_in[5];
    float* out = (float*)d_out;

    char* ws = (char*)d_ws;                     // needs ~6.7 MB
    _Float16* Hpack  = (_Float16*)ws;                               // 4 MB
    unsigned* maskw  = (unsigned*)(ws + (4u << 20));                // 2 MB
    float*    ddata  = (float*)(ws + (6u << 20));                   // 128 KB
    float*    esrc   = (float*)(ws + (6u << 20) + (128u << 10));    // 128 KB
    unsigned* Epk1   = (unsigned*)(ws + (6u << 20) + (256u << 10)); // 128 KB
    unsigned* Epk2   = (unsigned*)(ws + (6u << 20) + (384u << 10)); // 128 KB
    _Float16* F1     = (_Float16*)(ws + (6u << 20) + (512u << 10)); // 64 KB
    _Float16* F2     = (_Float16*)(ws + (6u << 20) + (576u << 10)); // 64 KB
    unsigned* dmax   = (unsigned*)(ws + (6u << 20) + (640u << 10));

    (void)hipMemsetAsync(dmax, 0, 8 * sizeof(unsigned), stream);
    hipLaunchKernelGGL(gat_prep, dim3(2560), dim3(256), 0, stream,
                       x, W, asrc, adst, adj, Hpack, ddata, esrc, dmax, maskw);
    hipLaunchKernelGGL(gat_ftab, dim3(128), dim3(256), 0, stream,
                       esrc, ddata, dmax, Epk1, Epk2, F1, F2);
    hipLaunchKernelGGL(gat_attn, dim3(1024), dim3(256), 0, stream,
                       maskw, Hpack, Epk1, Epk2, F1, F2, bias, out);
}

// Round 9
// 75.445 us; speedup vs baseline: 2.4441x; 1.4435x over previous
//
#include <hip/hip_runtime.h>
#include <hip/hip_bf16.h>
#include <hip/hip_fp16.h>

// DenseGAT fused kernel for MI355X.
// N=4096, IN=256, HEADS=8, D=64, C=512.
// Round 9: (a) attn 64 i-rows/wave, 4-way jc split per block (grid 512) ->
// 4x Hpack L2-reuse (1 GB -> 256 MB); (b) prep dmax atomics reduced 16x
// (block LDS reduce, one atomicMax per block; was 8192 same-line atomics).
//
// ws layout:
//   Hpack : _Float16 [8][128][4][64][8] @ 0        (4 MB)  H in B-frag order
//   maskw : uint     [4096][128]        @ 4M       (2 MB)  bit j&31 of word j>>5
//   ddata : float    [8][4096]          @ 6M       (128 KB) e_dst*log2e
//   esrc  : float    [4096][8]          @ 6M+128K  (128 KB)
//   Epk1  : uint     [8][4096]          @ 6M+256K  (128 KB) {E1,E1} f16x2
//   Epk2  : uint     [8][4096]          @ 6M+384K  (128 KB)
//   F1    : _Float16 [8][4096]          @ 6M+512K  (64 KB)
//   F2    : _Float16 [8][4096]          @ 6M+576K  (64 KB)
//   dmax  : uint     [8]                @ 6M+640K

#define GAT_N 4096
#define GAT_K 256
#define GAT_C 512
#define GAT_H 8
#define L2E 1.4426950408889634f

typedef _Float16 v8h __attribute__((ext_vector_type(8)));
typedef _Float16 f16x2 __attribute__((ext_vector_type(2)));
typedef float v4f __attribute__((ext_vector_type(4)));
typedef int v4i __attribute__((ext_vector_type(4)));

union U8 { v4i w; v8h h; };

static __device__ inline v4f mfma16(v8h a, v8h b, v4f c) {
    return __builtin_amdgcn_mfma_f32_16x16x32_f16(a, b, c, 0, 0, 0);
}

static __device__ inline unsigned pmax2(f16x2 e1, f16x2 e2, int f1w, int f2w) {
    f16x2 f1 = __builtin_bit_cast(f16x2, f1w);
    f16x2 f2 = __builtin_bit_cast(f16x2, f2w);
    f16x2 p1 = e1 * f1;
    f16x2 p2 = e2 * f2;
    f16x2 mx = __builtin_elementwise_max(p1, p2);
    return __builtin_bit_cast(unsigned, mx);
}

static __device__ inline float dmax_decode(unsigned du) {
    return __uint_as_float((du & 0x80000000u) ? (du & 0x7fffffffu) : ~du);
}

// -------- Phase A: projection + e_src/e_dst + Hpack, PLUS bitmask build ------
// grid 2560: blocks 0..511 = proj (64 mtiles x 8 heads), 512..2559 = mask.
__global__ __launch_bounds__(256) void gat_prep(
    const float* __restrict__ x, const float* __restrict__ W,
    const float* __restrict__ asrc, const float* __restrict__ adst,
    const int* __restrict__ adj,
    _Float16* __restrict__ Hpack, float* __restrict__ ddata,
    float* __restrict__ esrc, unsigned* __restrict__ dmax,
    unsigned* __restrict__ maskw)
{
    __shared__ float edl[4];
    const int bid = blockIdx.x;
    const int tid = threadIdx.x;

    if (bid >= 512) {
        // ---- mask path: lane covers 8 consecutive ints per iter; ALL loads
        // issued before any shfl (8 KB in flight per wave).
        const int g = (bid - 512) * 4 + (tid >> 6);     // wave 0..8191
        const int lane = tid & 63;
        const size_t base = (size_t)g * 2048;           // flat int index
        const int* pa = adj + base + (size_t)lane * 8;
        v4i v[8];
#pragma unroll
        for (int i = 0; i < 4; ++i) {
            v[2 * i]     = __builtin_nontemporal_load((const v4i*)(pa + (size_t)i * 512));
            v[2 * i + 1] = __builtin_nontemporal_load((const v4i*)(pa + (size_t)i * 512 + 4));
        }
#pragma unroll
        for (int i = 0; i < 4; ++i) {
            v4i a = v[2 * i], b = v[2 * i + 1];
            unsigned bits = (unsigned)(a.x > 0)        | ((unsigned)(a.y > 0) << 1)
                          | ((unsigned)(a.z > 0) << 2) | ((unsigned)(a.w > 0) << 3)
                          | ((unsigned)(b.x > 0) << 4) | ((unsigned)(b.y > 0) << 5)
                          | ((unsigned)(b.z > 0) << 6) | ((unsigned)(b.w > 0) << 7);
            unsigned w = bits << ((lane & 3) * 8);
            w |= __shfl_xor(w, 1);
            w |= __shfl_xor(w, 2);
            if ((lane & 3) == 0) maskw[(base >> 5) + i * 16 + (lane >> 2)] = w;
        }
        return;
    }

    // ---- projection path ----
    const int head = bid & 7, mtile = bid >> 3;
    const int wv = tid >> 6, l = tid & 63;
    const int dlow = l & 15, q = l >> 4;
    const int rowbase = mtile * 64 + wv * 16;
    const int arow = rowbase + dlow;

    v4f acc[4] = {};
#pragma unroll
    for (int kc = 0; kc < 8; ++kc) {
        const int k0 = kc * 32 + q * 8;
        const float4* ap = (const float4*)(x + (size_t)arow * GAT_K + k0);
        float4 xa = ap[0], xb = ap[1];
        v8h af;
        af[0] = (_Float16)xa.x; af[1] = (_Float16)xa.y; af[2] = (_Float16)xa.z; af[3] = (_Float16)xa.w;
        af[4] = (_Float16)xb.x; af[5] = (_Float16)xb.y; af[6] = (_Float16)xb.z; af[7] = (_Float16)xb.w;
#pragma unroll
        for (int nt = 0; nt < 4; ++nt) {
            const int c = head * 64 + nt * 16 + dlow;
            const float4* bp = (const float4*)(W + (size_t)c * GAT_K + k0);
            float4 wa = bp[0], wb = bp[1];
            v8h bf;
            bf[0] = (_Float16)wa.x; bf[1] = (_Float16)wa.y; bf[2] = (_Float16)wa.z; bf[3] = (_Float16)wa.w;
            bf[4] = (_Float16)wb.x; bf[5] = (_Float16)wb.y; bf[6] = (_Float16)wb.z; bf[7] = (_Float16)wb.w;
            acc[nt] = mfma16(af, bf, acc[nt]);
        }
    }

    float as[4], ad[4];
#pragma unroll
    for (int nt = 0; nt < 4; ++nt) {
        const int d = nt * 16 + dlow;
        as[nt] = asrc[head * 64 + d];
        ad[nt] = adst[head * 64 + d];
    }
    float es[4], ed[4];
#pragma unroll
    for (int r = 0; r < 4; ++r) {
        float se = 0.f, de = 0.f;
#pragma unroll
        for (int nt = 0; nt < 4; ++nt) { se += acc[nt][r] * as[nt]; de += acc[nt][r] * ad[nt]; }
#pragma unroll
        for (int m = 1; m < 16; m <<= 1) { se += __shfl_xor(se, m); de += __shfl_xor(de, m); }
        es[r] = se; ed[r] = de;
    }
    if (dlow == 0) {
#pragma unroll
        for (int r = 0; r < 4; ++r) {
            const int j = rowbase + q * 4 + r;
            esrc[j * GAT_H + head] = es[r];
            ddata[(size_t)head * GAT_N + j] = ed[r] * L2E;
        }
    }

    // block-level Dmax reduce: one atomic per block (was 16 same-line/block)
    {
        float wmax = fmaxf(fmaxf(ed[0], ed[1]), fmaxf(ed[2], ed[3]));
        wmax = fmaxf(wmax, __shfl_xor(wmax, 16));
        wmax = fmaxf(wmax, __shfl_xor(wmax, 32));
        if (l == 0) edl[wv] = wmax;
        __syncthreads();
        if (tid == 0) {
            float bm = fmaxf(fmaxf(edl[0], edl[1]), fmaxf(edl[2], edl[3]));
            unsigned u = __float_as_uint(bm);
            unsigned enc = (u & 0x80000000u) ? ~u : (u | 0x80000000u);
            atomicMax(dmax + head, enc);
        }
    }

    // Hpack: element (j, d) -> [head][j>>5][nt][(p>>3)*16 + dlow][p&7], p=j&31.
    const int jc = rowbase >> 5;
    const int p16 = rowbase & 16;
#pragma unroll
    for (int nt = 0; nt < 4; ++nt) {
#pragma unroll
        for (int rp = 0; rp < 4; rp += 2) {
            const int p = p16 + q * 4 + rp;
            const int qp = p >> 3, e = p & 7;
            const int lanep = qp * 16 + dlow;
            const size_t idx = ((((size_t)head * 128 + jc) * 4 + nt) * 64 + lanep) * 8 + e;
            union { unsigned u; _Float16 h[2]; } pk;
            pk.h[0] = (_Float16)acc[nt][rp];
            pk.h[1] = (_Float16)acc[nt][rp + 1];
            *(unsigned*)(Hpack + idx) = pk.u;
        }
    }
}

// -------- Phase A2: per-i and per-j exponential factor tables ---------------
__global__ __launch_bounds__(256) void gat_ftab(
    const float* __restrict__ esrc, const float* __restrict__ ddata,
    const unsigned* __restrict__ dmax,
    unsigned* __restrict__ Epk1, unsigned* __restrict__ Epk2,
    _Float16* __restrict__ F1, _Float16* __restrict__ F2)
{
    const int idx = blockIdx.x * 256 + threadIdx.x;   // head*4096 + i
    const int head = idx >> 12, i = idx & 4095;
    const float Dm = dmax_decode(dmax[head]);
    const float s = esrc[i * GAT_H + head];
    const float sm = s + Dm;
    const float M = fmaxf(sm, 0.2f * sm);
    const float e1 = __builtin_amdgcn_exp2f((sm - M) * L2E);
    const float e2 = __builtin_amdgcn_exp2f((0.2f * sm - M) * L2E);
    union { _Float16 h[2]; unsigned u; } pk;
    pk.h[0] = (_Float16)e1; pk.h[1] = (_Float16)e1; Epk1[idx] = pk.u;
    pk.h[0] = (_Float16)e2; pk.h[1] = (_Float16)e2; Epk2[idx] = pk.u;
    const float dl = ddata[idx] - Dm * L2E;           // (d - Dm)*log2e
    F1[idx] = (_Float16)__builtin_amdgcn_exp2f(dl);
    F2[idx] = (_Float16)__builtin_amdgcn_exp2f(0.2f * dl);
}

// ---------------- Phase B: fused mask + softmax + alpha@H -------------------
// grid 512 = (it = bid>>3, 64 rows) x (head = bid&7 -> XCD-pinned).
// block 256 (4 waves): ALL waves hold the full 64-row i-tile (4 E-pairs);
// wave wv takes jc chunks with jc%4 == wv -> each Hpack chunk loaded ONCE
// per block. No barriers in main loop; reg double-buffer; LDS tree combine.
__global__ __launch_bounds__(256, 2) void gat_attn(
    const unsigned* __restrict__ maskw, const _Float16* __restrict__ Hpack,
    const unsigned* __restrict__ Epk1, const unsigned* __restrict__ Epk2,
    const _Float16* __restrict__ F1, const _Float16* __restrict__ F2,
    const float* __restrict__ bias, float* __restrict__ out)
{
    // mask mlds[64 rows][132 words] (33.8 KB) unioned with xchg[2][64][81] (41.5 KB)
    __shared__ __align__(16) char smem[2 * 64 * 81 * 4];
    unsigned (*mlds)[132] = (unsigned (*)[132])smem;
    float* xch = (float*)smem;

    const int bid = blockIdx.x;
    const int head = bid & 7;
    const int it = bid >> 3;
    const int tid = threadIdx.x;
    const int wv = tid >> 6, l = tid & 63;
    const int dlow = l & 15, q = l >> 4, qs = q * 8;
    const int ibase = it * 64;

    // stage 64-row mask: mlds[row][word], thread t -> row t>>2, 32 words
    {
        const int r = tid >> 2;
        const int wq = (tid & 3) * 32;
        const unsigned* mp = maskw + (size_t)(ibase + r) * 128 + wq;
#pragma unroll
        for (int k = 0; k < 8; ++k) {
            v4i a = *(const v4i*)(mp + k * 4);
            *(v4i*)&mlds[r][wq + k * 4] = a;
        }
    }

    f16x2 E1p[4], E2p[4];
#pragma unroll
    for (int g = 0; g < 4; ++g) {
        E1p[g] = __builtin_bit_cast(f16x2, Epk1[head * GAT_N + ibase + g * 16 + dlow]);
        E2p[g] = __builtin_bit_cast(f16x2, Epk2[head * GAT_N + ibase + g * 16 + dlow]);
    }

    v4f accW[4][4] = {};
    v4f accZ[4] = {};
    v8h ones;
#pragma unroll
    for (int e = 0; e < 8; ++e) ones[e] = (_Float16)1.0f;

    const _Float16* Hl = Hpack + (size_t)head * 262144 + (size_t)l * 8;
    const _Float16* F1h = F1 + head * GAT_N;
    const _Float16* F2h = F2 + head * GAT_N;

    __syncthreads();   // mask visible; no barriers until epilogue

    unsigned Amw[4], Bmw[4];
    v4i Af1, Af2, Bf1, Bf2;
    v8h Ah[4], Bh[4];

#define GAT_LOAD(P, T) {                                                     \
        const int jc_ = (T) * 4 + wv;                                        \
        _Pragma("unroll")                                                    \
        for (int g = 0; g < 4; ++g) P##mw[g] = mlds[g * 16 + dlow][jc_];     \
        const int kg_ = (jc_ << 5) + qs;                                     \
        P##f1 = *(const v4i*)(F1h + kg_);                                    \
        P##f2 = *(const v4i*)(F2h + kg_);                                    \
        const _Float16* hp_ = Hl + (size_t)jc_ * 2048;                       \
        P##h[0] = *(const v8h*)(hp_);                                        \
        P##h[1] = *(const v8h*)(hp_ + 512);                                  \
        P##h[2] = *(const v8h*)(hp_ + 1024);                                 \
        P##h[3] = *(const v8h*)(hp_ + 1536);                                 \
    }

    // byte-smear (4-bit fields only -> carry-free; see R8 note)
#define GAT_COMP(P) {                                                        \
        _Pragma("unroll")                                                    \
        for (int g = 0; g < 4; ++g) {                                        \
            const unsigned b8_ = (P##mw[g] >> qs) & 255u;                    \
            const unsigned z1_ = (((b8_ & 15u) * 0x204081u) << 7) & 0x80808080u; \
            const unsigned z2_ = (((b8_ >> 4) * 0x204081u) << 7) & 0x80808080u;  \
            const unsigned m1_ = (z1_ >> 7) * 255u;                          \
            const unsigned m2_ = (z2_ >> 7) * 255u;                          \
            U8 fr_;                                                          \
            fr_.w[0] = (int)(pmax2(E1p[g], E2p[g], P##f1[0], P##f2[0])       \
                             & __builtin_amdgcn_perm(0u, m1_, 0x01010000u)); \
            fr_.w[1] = (int)(pmax2(E1p[g], E2p[g], P##f1[1], P##f2[1])       \
                             & __builtin_amdgcn_perm(0u, m1_, 0x03030202u)); \
            fr_.w[2] = (int)(pmax2(E1p[g], E2p[g], P##f1[2], P##f2[2])       \
                             & __builtin_amdgcn_perm(0u, m2_, 0x01010000u)); \
            fr_.w[3] = (int)(pmax2(E1p[g], E2p[g], P##f1[3], P##f2[3])       \
                             & __builtin_amdgcn_perm(0u, m2_, 0x03030202u)); \
            accW[g][0] = mfma16(fr_.h, P##h[0], accW[g][0]);                 \
            accW[g][1] = mfma16(fr_.h, P##h[1], accW[g][1]);                 \
            accW[g][2] = mfma16(fr_.h, P##h[2], accW[g][2]);                 \
            accW[g][3] = mfma16(fr_.h, P##h[3], accW[g][3]);                 \
            accZ[g]    = mfma16(fr_.h, ones,  accZ[g]);                      \
        }                                                                    \
    }

    GAT_LOAD(A, 0)
    for (int t = 0; t < 30; t += 2) {
        GAT_LOAD(B, t + 1)
        GAT_COMP(A)
        GAT_LOAD(A, t + 2)
        GAT_COMP(B)
    }
    GAT_LOAD(B, 31)
    GAT_COMP(A)
    GAT_COMP(B)
#undef GAT_LOAD
#undef GAT_COMP

    // ---- 4-way j-partial combine: tree through LDS (reuses mask space) ----
    __syncthreads();
    {
        float* xb = xch + ((size_t)(wv >> 1) * 64 + l) * 81;
        if (wv & 1) {   // waves 1,3 write
#pragma unroll
            for (int g = 0; g < 4; ++g) {
#pragma unroll
                for (int nt = 0; nt < 4; ++nt)
#pragma unroll
                    for (int r = 0; r < 4; ++r) xb[(g * 4 + nt) * 4 + r] = accW[g][nt][r];
#pragma unroll
                for (int r = 0; r < 4; ++r) xb[64 + g * 4 + r] = accZ[g][r];
            }
        }
        __syncthreads();
        if (!(wv & 1)) {   // waves 0,2 reduce
#pragma unroll
            for (int g = 0; g < 4; ++g) {
#pragma unroll
                for (int nt = 0; nt < 4; ++nt)
#pragma unroll
                    for (int r = 0; r < 4; ++r) accW[g][nt][r] += xb[(g * 4 + nt) * 4 + r];
#pragma unroll
                for (int r = 0; r < 4; ++r) accZ[g][r] += xb[64 + g * 4 + r];
            }
        }
        __syncthreads();
        float* x0 = xch + (size_t)l * 81;
        if (wv == 2) {   // wave 2 writes its reduced partial
#pragma unroll
            for (int g = 0; g < 4; ++g) {
#pragma unroll
                for (int nt = 0; nt < 4; ++nt)
#pragma unroll
                    for (int r = 0; r < 4; ++r) x0[(g * 4 + nt) * 4 + r] = accW[g][nt][r];
#pragma unroll
                for (int r = 0; r < 4; ++r) x0[64 + g * 4 + r] = accZ[g][r];
            }
        }
        __syncthreads();
        if (wv == 0) {
#pragma unroll
            for (int g = 0; g < 4; ++g) {
#pragma unroll
                for (int nt = 0; nt < 4; ++nt)
#pragma unroll
                    for (int r = 0; r < 4; ++r) accW[g][nt][r] += x0[(g * 4 + nt) * 4 + r];
#pragma unroll
                for (int r = 0; r < 4; ++r) accZ[g][r] += x0[64 + g * 4 + r];
            }
#pragma unroll
            for (int g = 0; g < 4; ++g) {
                float zi[4];
#pragma unroll
                for (int r = 0; r < 4; ++r) zi[r] = 1.0f / accZ[g][r];
#pragma unroll
                for (int nt = 0; nt < 4; ++nt) {
                    const int col = head * 64 + nt * 16 + dlow;
                    const float b = bias[col];
#pragma unroll
                    for (int r = 0; r < 4; ++r) {
                        const int row = ibase + g * 16 + q * 4 + r;
                        out[(size_t)row * GAT_C + col] = accW[g][nt][r] * zi[r] + b;
                    }
                }
            }
        }
    }
}

extern "C" void kernel_launch(void* const* d_in, const int* in_sizes, int n_in,
                              void* d_out, int out_size, void* d_ws, size_t ws_size,
                              hipStream_t stream) {
    const float* x    = (const float*)d_in[0];
    const int*   adj  = (const int*)d_in[1];
    const float* W    = (const float*)d_in[2];
    const float* asrc = (const float*)d_in[3];
    const float* adst = (const float*)d_in[4];
    const float* bias = (const float*)d_in[5];
    float* out = (float*)d_out;

    char* ws = (char*)d_ws;                     // needs ~6.7 MB
    _Float16* Hpack  = (_Float16*)ws;                               // 4 MB
    unsigned* maskw  = (unsigned*)(ws + (4u << 20));                // 2 MB
    float*    ddata  = (float*)(ws + (6u << 20));                   // 128 KB
    float*    esrc   = (float*)(ws + (6u << 20) + (128u << 10));    // 128 KB
    unsigned* Epk1   = (unsigned*)(ws + (6u << 20) + (256u << 10)); // 128 KB
    unsigned* Epk2   = (unsigned*)(ws + (6u << 20) + (384u << 10)); // 128 KB
    _Float16* F1     = (_Float16*)(ws + (6u << 20) + (512u << 10)); // 64 KB
    _Float16* F2     = (_Float16*)(ws + (6u << 20) + (576u << 10)); // 64 KB
    unsigned* dmax   = (unsigned*)(ws + (6u << 20) + (640u << 10));

    (void)hipMemsetAsync(dmax, 0, 8 * sizeof(unsigned), stream);
    hipLaunchKernelGGL(gat_prep, dim3(2560), dim3(256), 0, stream,
                       x, W, asrc, adst, adj, Hpack, ddata, esrc, dmax, maskw);
    hipLaunchKernelGGL(gat_ftab, dim3(128), dim3(256), 0, stream,
                       esrc, ddata, dmax, Epk1, Epk2, F1, F2);
    hipLaunchKernelGGL(gat_attn, dim3(512), dim3(256), 0, stream,
                       maskw, Hpack, Epk1, Epk2, F1, F2, bias, out);
}

// Round 10
// 69.066 us; speedup vs baseline: 2.6699x; 1.0924x over previous
//
#include <hip/hip_runtime.h>
#include <hip/hip_bf16.h>
#include <hip/hip_fp16.h>

// DenseGAT fused kernel for MI355X.
// N=4096, IN=256, HEADS=8, D=64, C=512.
// Round 10: remove the 32-B hipMemsetAsync (measured ~39.7 us per replay as
// an in-graph fillBufferAligned!) and the dmax atomic chain entirely:
// gat_ftab now reduces the per-head max itself (redundant 16 KB L2 read per
// block + shfl/LDS tree). prep/attn unchanged from Round 9.
//
// ws layout:
//   Hpack : _Float16 [8][128][4][64][8] @ 0        (4 MB)  H in B-frag order
//   maskw : uint     [4096][128]        @ 4M       (2 MB)  bit j&31 of word j>>5
//   ddata : float    [8][4096]          @ 6M       (128 KB) e_dst*log2e
//   esrc  : float    [4096][8]          @ 6M+128K  (128 KB)
//   Epk1  : uint     [8][4096]          @ 6M+256K  (128 KB) {E1,E1} f16x2
//   Epk2  : uint     [8][4096]          @ 6M+384K  (128 KB)
//   F1    : _Float16 [8][4096]          @ 6M+512K  (64 KB)
//   F2    : _Float16 [8][4096]          @ 6M+576K  (64 KB)

#define GAT_N 4096
#define GAT_K 256
#define GAT_C 512
#define GAT_H 8
#define L2E 1.4426950408889634f
#define LN2 0.6931471805599453f

typedef _Float16 v8h __attribute__((ext_vector_type(8)));
typedef _Float16 f16x2 __attribute__((ext_vector_type(2)));
typedef float v4f __attribute__((ext_vector_type(4)));
typedef int v4i __attribute__((ext_vector_type(4)));

union U8 { v4i w; v8h h; };

static __device__ inline v4f mfma16(v8h a, v8h b, v4f c) {
    return __builtin_amdgcn_mfma_f32_16x16x32_f16(a, b, c, 0, 0, 0);
}

static __device__ inline unsigned pmax2(f16x2 e1, f16x2 e2, int f1w, int f2w) {
    f16x2 f1 = __builtin_bit_cast(f16x2, f1w);
    f16x2 f2 = __builtin_bit_cast(f16x2, f2w);
    f16x2 p1 = e1 * f1;
    f16x2 p2 = e2 * f2;
    f16x2 mx = __builtin_elementwise_max(p1, p2);
    return __builtin_bit_cast(unsigned, mx);
}

// -------- Phase A: projection + e_src/e_dst + Hpack, PLUS bitmask build ------
// grid 2560: blocks 0..511 = proj (64 mtiles x 8 heads), 512..2559 = mask.
__global__ __launch_bounds__(256) void gat_prep(
    const float* __restrict__ x, const float* __restrict__ W,
    const float* __restrict__ asrc, const float* __restrict__ adst,
    const int* __restrict__ adj,
    _Float16* __restrict__ Hpack, float* __restrict__ ddata,
    float* __restrict__ esrc, unsigned* __restrict__ maskw)
{
    const int bid = blockIdx.x;
    const int tid = threadIdx.x;

    if (bid >= 512) {
        // ---- mask path: lane covers 8 consecutive ints per iter; ALL loads
        // issued before any shfl (8 KB in flight per wave).
        const int g = (bid - 512) * 4 + (tid >> 6);     // wave 0..8191
        const int lane = tid & 63;
        const size_t base = (size_t)g * 2048;           // flat int index
        const int* pa = adj + base + (size_t)lane * 8;
        v4i v[8];
#pragma unroll
        for (int i = 0; i < 4; ++i) {
            v[2 * i]     = __builtin_nontemporal_load((const v4i*)(pa + (size_t)i * 512));
            v[2 * i + 1] = __builtin_nontemporal_load((const v4i*)(pa + (size_t)i * 512 + 4));
        }
#pragma unroll
        for (int i = 0; i < 4; ++i) {
            v4i a = v[2 * i], b = v[2 * i + 1];
            unsigned bits = (unsigned)(a.x > 0)        | ((unsigned)(a.y > 0) << 1)
                          | ((unsigned)(a.z > 0) << 2) | ((unsigned)(a.w > 0) << 3)
                          | ((unsigned)(b.x > 0) << 4) | ((unsigned)(b.y > 0) << 5)
                          | ((unsigned)(b.z > 0) << 6) | ((unsigned)(b.w > 0) << 7);
            unsigned w = bits << ((lane & 3) * 8);
            w |= __shfl_xor(w, 1);
            w |= __shfl_xor(w, 2);
            if ((lane & 3) == 0) maskw[(base >> 5) + i * 16 + (lane >> 2)] = w;
        }
        return;
    }

    // ---- projection path ----
    const int head = bid & 7, mtile = bid >> 3;
    const int wv = tid >> 6, l = tid & 63;
    const int dlow = l & 15, q = l >> 4;
    const int rowbase = mtile * 64 + wv * 16;
    const int arow = rowbase + dlow;

    v4f acc[4] = {};
#pragma unroll
    for (int kc = 0; kc < 8; ++kc) {
        const int k0 = kc * 32 + q * 8;
        const float4* ap = (const float4*)(x + (size_t)arow * GAT_K + k0);
        float4 xa = ap[0], xb = ap[1];
        v8h af;
        af[0] = (_Float16)xa.x; af[1] = (_Float16)xa.y; af[2] = (_Float16)xa.z; af[3] = (_Float16)xa.w;
        af[4] = (_Float16)xb.x; af[5] = (_Float16)xb.y; af[6] = (_Float16)xb.z; af[7] = (_Float16)xb.w;
#pragma unroll
        for (int nt = 0; nt < 4; ++nt) {
            const int c = head * 64 + nt * 16 + dlow;
            const float4* bp = (const float4*)(W + (size_t)c * GAT_K + k0);
            float4 wa = bp[0], wb = bp[1];
            v8h bf;
            bf[0] = (_Float16)wa.x; bf[1] = (_Float16)wa.y; bf[2] = (_Float16)wa.z; bf[3] = (_Float16)wa.w;
            bf[4] = (_Float16)wb.x; bf[5] = (_Float16)wb.y; bf[6] = (_Float16)wb.z; bf[7] = (_Float16)wb.w;
            acc[nt] = mfma16(af, bf, acc[nt]);
        }
    }

    float as[4], ad[4];
#pragma unroll
    for (int nt = 0; nt < 4; ++nt) {
        const int d = nt * 16 + dlow;
        as[nt] = asrc[head * 64 + d];
        ad[nt] = adst[head * 64 + d];
    }
    float es[4], ed[4];
#pragma unroll
    for (int r = 0; r < 4; ++r) {
        float se = 0.f, de = 0.f;
#pragma unroll
        for (int nt = 0; nt < 4; ++nt) { se += acc[nt][r] * as[nt]; de += acc[nt][r] * ad[nt]; }
#pragma unroll
        for (int m = 1; m < 16; m <<= 1) { se += __shfl_xor(se, m); de += __shfl_xor(de, m); }
        es[r] = se; ed[r] = de;
    }
    if (dlow == 0) {
#pragma unroll
        for (int r = 0; r < 4; ++r) {
            const int j = rowbase + q * 4 + r;
            esrc[j * GAT_H + head] = es[r];
            ddata[(size_t)head * GAT_N + j] = ed[r] * L2E;
        }
    }

    // Hpack: element (j, d) -> [head][j>>5][nt][(p>>3)*16 + dlow][p&7], p=j&31.
    const int jc = rowbase >> 5;
    const int p16 = rowbase & 16;
#pragma unroll
    for (int nt = 0; nt < 4; ++nt) {
#pragma unroll
        for (int rp = 0; rp < 4; rp += 2) {
            const int p = p16 + q * 4 + rp;
            const int qp = p >> 3, e = p & 7;
            const int lanep = qp * 16 + dlow;
            const size_t idx = ((((size_t)head * 128 + jc) * 4 + nt) * 64 + lanep) * 8 + e;
            union { unsigned u; _Float16 h[2]; } pk;
            pk.h[0] = (_Float16)acc[nt][rp];
            pk.h[1] = (_Float16)acc[nt][rp + 1];
            *(unsigned*)(Hpack + idx) = pk.u;
        }
    }
}

// -------- Phase A2: per-i and per-j exponential factor tables ---------------
// grid 128 = 8 heads x 16 slices. Each block redundantly reduces its head's
// max over ddata (scaled by log2e; same argmax), then fills its 256-entry
// slice. No atomics, no init dependency.
// E1 = exp(s+Dm-M), E2 = exp(0.2s+0.2Dm-M), M = leaky(s+Dm)  (per head,i)
// F1 = exp(d-Dm),   F2 = exp(0.2(d-Dm))                       (per head,j)
__global__ __launch_bounds__(256) void gat_ftab(
    const float* __restrict__ esrc, const float* __restrict__ ddata,
    unsigned* __restrict__ Epk1, unsigned* __restrict__ Epk2,
    _Float16* __restrict__ F1, _Float16* __restrict__ F2)
{
    __shared__ float wmax[4];
    const int bid = blockIdx.x;
    const int tid = threadIdx.x;
    const int head = bid >> 4;
    const float* dh = ddata + head * GAT_N;

    // per-head max of ddata (= max_ed * log2e)
    float m = -3.4e38f;
    {
        const v4f* dp = (const v4f*)(dh + tid * 16);
#pragma unroll
        for (int k = 0; k < 4; ++k) {
            v4f v = dp[k];
            m = fmaxf(m, fmaxf(fmaxf(v[0], v[1]), fmaxf(v[2], v[3])));
        }
    }
#pragma unroll
    for (int s = 1; s < 64; s <<= 1) m = fmaxf(m, __shfl_xor(m, s));
    if ((tid & 63) == 0) wmax[tid >> 6] = m;
    __syncthreads();
    const float Dml = fmaxf(fmaxf(wmax[0], wmax[1]), fmaxf(wmax[2], wmax[3]));
    const float Dm = Dml * LN2;                     // unscale: /log2e

    const int i = (bid & 15) * 256 + tid;
    const int idx = head * GAT_N + i;
    const float s = esrc[i * GAT_H + head];
    const float sm = s + Dm;
    const float M = fmaxf(sm, 0.2f * sm);
    const float e1 = __builtin_amdgcn_exp2f((sm - M) * L2E);
    const float e2 = __builtin_amdgcn_exp2f((0.2f * sm - M) * L2E);
    union { _Float16 h[2]; unsigned u; } pk;
    pk.h[0] = (_Float16)e1; pk.h[1] = (_Float16)e1; Epk1[idx] = pk.u;
    pk.h[0] = (_Float16)e2; pk.h[1] = (_Float16)e2; Epk2[idx] = pk.u;
    const float dl = dh[i] - Dml;                   // (d - Dm)*log2e
    F1[idx] = (_Float16)__builtin_amdgcn_exp2f(dl);
    F2[idx] = (_Float16)__builtin_amdgcn_exp2f(0.2f * dl);
}

// ---------------- Phase B: fused mask + softmax + alpha@H -------------------
// grid 512 = (it = bid>>3, 64 rows) x (head = bid&7 -> XCD-pinned).
// block 256 (4 waves): ALL waves hold the full 64-row i-tile (4 E-pairs);
// wave wv takes jc chunks with jc%4 == wv -> each Hpack chunk loaded ONCE
// per block. No barriers in main loop; reg double-buffer; LDS tree combine.
__global__ __launch_bounds__(256, 2) void gat_attn(
    const unsigned* __restrict__ maskw, const _Float16* __restrict__ Hpack,
    const unsigned* __restrict__ Epk1, const unsigned* __restrict__ Epk2,
    const _Float16* __restrict__ F1, const _Float16* __restrict__ F2,
    const float* __restrict__ bias, float* __restrict__ out)
{
    // mask mlds[64 rows][132 words] (33.8 KB) unioned with xchg[2][64][81] (41.5 KB)
    __shared__ __align__(16) char smem[2 * 64 * 81 * 4];
    unsigned (*mlds)[132] = (unsigned (*)[132])smem;
    float* xch = (float*)smem;

    const int bid = blockIdx.x;
    const int head = bid & 7;
    const int it = bid >> 3;
    const int tid = threadIdx.x;
    const int wv = tid >> 6, l = tid & 63;
    const int dlow = l & 15, q = l >> 4, qs = q * 8;
    const int ibase = it * 64;

    // stage 64-row mask: mlds[row][word], thread t -> row t>>2, 32 words
    {
        const int r = tid >> 2;
        const int wq = (tid & 3) * 32;
        const unsigned* mp = maskw + (size_t)(ibase + r) * 128 + wq;
#pragma unroll
        for (int k = 0; k < 8; ++k) {
            v4i a = *(const v4i*)(mp + k * 4);
            *(v4i*)&mlds[r][wq + k * 4] = a;
        }
    }

    f16x2 E1p[4], E2p[4];
#pragma unroll
    for (int g = 0; g < 4; ++g) {
        E1p[g] = __builtin_bit_cast(f16x2, Epk1[head * GAT_N + ibase + g * 16 + dlow]);
        E2p[g] = __builtin_bit_cast(f16x2, Epk2[head * GAT_N + ibase + g * 16 + dlow]);
    }

    v4f accW[4][4] = {};
    v4f accZ[4] = {};
    v8h ones;
#pragma unroll
    for (int e = 0; e < 8; ++e) ones[e] = (_Float16)1.0f;

    const _Float16* Hl = Hpack + (size_t)head * 262144 + (size_t)l * 8;
    const _Float16* F1h = F1 + head * GAT_N;
    const _Float16* F2h = F2 + head * GAT_N;

    __syncthreads();   // mask visible; no barriers until epilogue

    unsigned Amw[4], Bmw[4];
    v4i Af1, Af2, Bf1, Bf2;
    v8h Ah[4], Bh[4];

#define GAT_LOAD(P, T) {                                                     \
        const int jc_ = (T) * 4 + wv;                                        \
        _Pragma("unroll")                                                    \
        for (int g = 0; g < 4; ++g) P##mw[g] = mlds[g * 16 + dlow][jc_];     \
        const int kg_ = (jc_ << 5) + qs;                                     \
        P##f1 = *(const v4i*)(F1h + kg_);                                    \
        P##f2 = *(const v4i*)(F2h + kg_);                                    \
        const _Float16* hp_ = Hl + (size_t)jc_ * 2048;                       \
        P##h[0] = *(const v8h*)(hp_);                                        \
        P##h[1] = *(const v8h*)(hp_ + 512);                                  \
        P##h[2] = *(const v8h*)(hp_ + 1024);                                 \
        P##h[3] = *(const v8h*)(hp_ + 1536);                                 \
    }

    // byte-smear (4-bit fields only -> carry-free; see R8 note)
#define GAT_COMP(P) {                                                        \
        _Pragma("unroll")                                                    \
        for (int g = 0; g < 4; ++g) {                                        \
            const unsigned b8_ = (P##mw[g] >> qs) & 255u;                    \
            const unsigned z1_ = (((b8_ & 15u) * 0x204081u) << 7) & 0x80808080u; \
            const unsigned z2_ = (((b8_ >> 4) * 0x204081u) << 7) & 0x80808080u;  \
            const unsigned m1_ = (z1_ >> 7) * 255u;                          \
            const unsigned m2_ = (z2_ >> 7) * 255u;                          \
            U8 fr_;                                                          \
            fr_.w[0] = (int)(pmax2(E1p[g], E2p[g], P##f1[0], P##f2[0])       \
                             & __builtin_amdgcn_perm(0u, m1_, 0x01010000u)); \
            fr_.w[1] = (int)(pmax2(E1p[g], E2p[g], P##f1[1], P##f2[1])       \
                             & __builtin_amdgcn_perm(0u, m1_, 0x03030202u)); \
            fr_.w[2] = (int)(pmax2(E1p[g], E2p[g], P##f1[2], P##f2[2])       \
                             & __builtin_amdgcn_perm(0u, m2_, 0x01010000u)); \
            fr_.w[3] = (int)(pmax2(E1p[g], E2p[g], P##f1[3], P##f2[3])       \
                             & __builtin_amdgcn_perm(0u, m2_, 0x03030202u)); \
            accW[g][0] = mfma16(fr_.h, P##h[0], accW[g][0]);                 \
            accW[g][1] = mfma16(fr_.h, P##h[1], accW[g][1]);                 \
            accW[g][2] = mfma16(fr_.h, P##h[2], accW[g][2]);                 \
            accW[g][3] = mfma16(fr_.h, P##h[3], accW[g][3]);                 \
            accZ[g]    = mfma16(fr_.h, ones,  accZ[g]);                      \
        }                                                                    \
    }

    GAT_LOAD(A, 0)
    for (int t = 0; t < 30; t += 2) {
        GAT_LOAD(B, t + 1)
        GAT_COMP(A)
        GAT_LOAD(A, t + 2)
        GAT_COMP(B)
    }
    GAT_LOAD(B, 31)
    GAT_COMP(A)
    GAT_COMP(B)
#undef GAT_LOAD
#undef GAT_COMP

    // ---- 4-way j-partial combine: tree through LDS (reuses mask space) ----
    __syncthreads();
    {
        float* xb = xch + ((size_t)(wv >> 1) * 64 + l) * 81;
        if (wv & 1) {   // waves 1,3 write
#pragma unroll
            for (int g = 0; g < 4; ++g) {
#pragma unroll
                for (int nt = 0; nt < 4; ++nt)
#pragma unroll
                    for (int r = 0; r < 4; ++r) xb[(g * 4 + nt) * 4 + r] = accW[g][nt][r];
#pragma unroll
                for (int r = 0; r < 4; ++r) xb[64 + g * 4 + r] = accZ[g][r];
            }
        }
        __syncthreads();
        if (!(wv & 1)) {   // waves 0,2 reduce
#pragma unroll
            for (int g = 0; g < 4; ++g) {
#pragma unroll
                for (int nt = 0; nt < 4; ++nt)
#pragma unroll
                    for (int r = 0; r < 4; ++r) accW[g][nt][r] += xb[(g * 4 + nt) * 4 + r];
#pragma unroll
                for (int r = 0; r < 4; ++r) accZ[g][r] += xb[64 + g * 4 + r];
            }
        }
        __syncthreads();
        float* x0 = xch + (size_t)l * 81;
        if (wv == 2) {   // wave 2 writes its reduced partial
#pragma unroll
            for (int g = 0; g < 4; ++g) {
#pragma unroll
                for (int nt = 0; nt < 4; ++nt)
#pragma unroll
                    for (int r = 0; r < 4; ++r) x0[(g * 4 + nt) * 4 + r] = accW[g][nt][r];
#pragma unroll
                for (int r = 0; r < 4; ++r) x0[64 + g * 4 + r] = accZ[g][r];
            }
        }
        __syncthreads();
        if (wv == 0) {
#pragma unroll
            for (int g = 0; g < 4; ++g) {
#pragma unroll
                for (int nt = 0; nt < 4; ++nt)
#pragma unroll
                    for (int r = 0; r < 4; ++r) accW[g][nt][r] += x0[(g * 4 + nt) * 4 + r];
#pragma unroll
                for (int r = 0; r < 4; ++r) accZ[g][r] += x0[64 + g * 4 + r];
            }
#pragma unroll
            for (int g = 0; g < 4; ++g) {
                float zi[4];
#pragma unroll
                for (int r = 0; r < 4; ++r) zi[r] = 1.0f / accZ[g][r];
#pragma unroll
                for (int nt = 0; nt < 4; ++nt) {
                    const int col = head * 64 + nt * 16 + dlow;
                    const float b = bias[col];
#pragma unroll
                    for (int r = 0; r < 4; ++r) {
                        const int row = ibase + g * 16 + q * 4 + r;
                        out[(size_t)row * GAT_C + col] = accW[g][nt][r] * zi[r] + b;
                    }
                }
            }
        }
    }
}

extern "C" void kernel_launch(void* const* d_in, const int* in_sizes, int n_in,
                              void* d_out, int out_size, void* d_ws, size_t ws_size,
                              hipStream_t stream) {
    const float* x    = (const float*)d_in[0];
    const int*   adj  = (const int*)d_in[1];
    const float* W    = (const float*)d_in[2];
    const float* asrc = (const float*)d_in[3];
    const float* adst = (const float*)d_in[4];
    const float* bias = (const float*)d_in[5];
    float* out = (float*)d_out;

    char* ws = (char*)d_ws;                     // needs ~6.7 MB
    _Float16* Hpack  = (_Float16*)ws;                               // 4 MB
    unsigned* maskw  = (unsigned*)(ws + (4u << 20));                // 2 MB
    float*    ddata  = (float*)(ws + (6u << 20));                   // 128 KB
    float*    esrc   = (float*)(ws + (6u << 20) + (128u << 10));    // 128 KB
    unsigned* Epk1   = (unsigned*)(ws + (6u << 20) + (256u << 10)); // 128 KB
    unsigned* Epk2   = (unsigned*)(ws + (6u << 20) + (384u << 10)); // 128 KB
    _Float16* F1     = (_Float16*)(ws + (6u << 20) + (512u << 10)); // 64 KB
    _Float16* F2     = (_Float16*)(ws + (6u << 20) + (576u << 10)); // 64 KB

    hipLaunchKernelGGL(gat_prep, dim3(2560), dim3(256), 0, stream,
                       x, W, asrc, adst, adj, Hpack, ddata, esrc, maskw);
    hipLaunchKernelGGL(gat_ftab, dim3(128), dim3(256), 0, stream,
                       esrc, ddata, Epk1, Epk2, F1, F2);
    hipLaunchKernelGGL(gat_attn, dim3(512), dim3(256), 0, stream,
                       maskw, Hpack, Epk1, Epk2, F1, F2, bias, out);
}

// Round 11
// 64.427 us; speedup vs baseline: 2.8621x; 1.0720x over previous
//
#include <hip/hip_runtime.h>
#include <hip/hip_bf16.h>
#include <hip/hip_fp16.h>

// DenseGAT fused kernel for MI355X.
// N=4096, IN=256, HEADS=8, D=64, C=512.
// Round 11: remove __builtin_nontemporal_load from the adjacency mask path.
// prep has been stuck ~45-50us across three load-shape rewrites (HBM floor
// 10.5us); the one survivor is the nt cache policy on the 64MB stream --
// suspected to defeat L2 line aggregation (R5: 768 GB/s with idle VALU).
// Everything else identical to Round 10.
//
// ws layout:
//   Hpack : _Float16 [8][128][4][64][8] @ 0        (4 MB)  H in B-frag order
//   maskw : uint     [4096][128]        @ 4M       (2 MB)  bit j&31 of word j>>5
//   ddata : float    [8][4096]          @ 6M       (128 KB) e_dst*log2e
//   esrc  : float    [4096][8]          @ 6M+128K  (128 KB)
//   Epk1  : uint     [8][4096]          @ 6M+256K  (128 KB) {E1,E1} f16x2
//   Epk2  : uint     [8][4096]          @ 6M+384K  (128 KB)
//   F1    : _Float16 [8][4096]          @ 6M+512K  (64 KB)
//   F2    : _Float16 [8][4096]          @ 6M+576K  (64 KB)

#define GAT_N 4096
#define GAT_K 256
#define GAT_C 512
#define GAT_H 8
#define L2E 1.4426950408889634f
#define LN2 0.6931471805599453f

typedef _Float16 v8h __attribute__((ext_vector_type(8)));
typedef _Float16 f16x2 __attribute__((ext_vector_type(2)));
typedef float v4f __attribute__((ext_vector_type(4)));
typedef int v4i __attribute__((ext_vector_type(4)));

union U8 { v4i w; v8h h; };

static __device__ inline v4f mfma16(v8h a, v8h b, v4f c) {
    return __builtin_amdgcn_mfma_f32_16x16x32_f16(a, b, c, 0, 0, 0);
}

static __device__ inline unsigned pmax2(f16x2 e1, f16x2 e2, int f1w, int f2w) {
    f16x2 f1 = __builtin_bit_cast(f16x2, f1w);
    f16x2 f2 = __builtin_bit_cast(f16x2, f2w);
    f16x2 p1 = e1 * f1;
    f16x2 p2 = e2 * f2;
    f16x2 mx = __builtin_elementwise_max(p1, p2);
    return __builtin_bit_cast(unsigned, mx);
}

// -------- Phase A: projection + e_src/e_dst + Hpack, PLUS bitmask build ------
// grid 2560: blocks 0..511 = proj (64 mtiles x 8 heads), 512..2559 = mask.
__global__ __launch_bounds__(256) void gat_prep(
    const float* __restrict__ x, const float* __restrict__ W,
    const float* __restrict__ asrc, const float* __restrict__ adst,
    const int* __restrict__ adj,
    _Float16* __restrict__ Hpack, float* __restrict__ ddata,
    float* __restrict__ esrc, unsigned* __restrict__ maskw)
{
    const int bid = blockIdx.x;
    const int tid = threadIdx.x;

    if (bid >= 512) {
        // ---- mask path: lane covers 8 consecutive ints per iter; ALL loads
        // issued before any shfl (8 KB in flight per wave). Regular cached
        // loads (nt removed -- R11).
        const int g = (bid - 512) * 4 + (tid >> 6);     // wave 0..8191
        const int lane = tid & 63;
        const size_t base = (size_t)g * 2048;           // flat int index
        const int* pa = adj + base + (size_t)lane * 8;
        v4i v[8];
#pragma unroll
        for (int i = 0; i < 4; ++i) {
            v[2 * i]     = *(const v4i*)(pa + (size_t)i * 512);
            v[2 * i + 1] = *(const v4i*)(pa + (size_t)i * 512 + 4);
        }
#pragma unroll
        for (int i = 0; i < 4; ++i) {
            v4i a = v[2 * i], b = v[2 * i + 1];
            unsigned bits = (unsigned)(a.x > 0)        | ((unsigned)(a.y > 0) << 1)
                          | ((unsigned)(a.z > 0) << 2) | ((unsigned)(a.w > 0) << 3)
                          | ((unsigned)(b.x > 0) << 4) | ((unsigned)(b.y > 0) << 5)
                          | ((unsigned)(b.z > 0) << 6) | ((unsigned)(b.w > 0) << 7);
            unsigned w = bits << ((lane & 3) * 8);
            w |= __shfl_xor(w, 1);
            w |= __shfl_xor(w, 2);
            if ((lane & 3) == 0) maskw[(base >> 5) + i * 16 + (lane >> 2)] = w;
        }
        return;
    }

    // ---- projection path ----
    const int head = bid & 7, mtile = bid >> 3;
    const int wv = tid >> 6, l = tid & 63;
    const int dlow = l & 15, q = l >> 4;
    const int rowbase = mtile * 64 + wv * 16;
    const int arow = rowbase + dlow;

    v4f acc[4] = {};
#pragma unroll
    for (int kc = 0; kc < 8; ++kc) {
        const int k0 = kc * 32 + q * 8;
        const float4* ap = (const float4*)(x + (size_t)arow * GAT_K + k0);
        float4 xa = ap[0], xb = ap[1];
        v8h af;
        af[0] = (_Float16)xa.x; af[1] = (_Float16)xa.y; af[2] = (_Float16)xa.z; af[3] = (_Float16)xa.w;
        af[4] = (_Float16)xb.x; af[5] = (_Float16)xb.y; af[6] = (_Float16)xb.z; af[7] = (_Float16)xb.w;
#pragma unroll
        for (int nt = 0; nt < 4; ++nt) {
            const int c = head * 64 + nt * 16 + dlow;
            const float4* bp = (const float4*)(W + (size_t)c * GAT_K + k0);
            float4 wa = bp[0], wb = bp[1];
            v8h bf;
            bf[0] = (_Float16)wa.x; bf[1] = (_Float16)wa.y; bf[2] = (_Float16)wa.z; bf[3] = (_Float16)wa.w;
            bf[4] = (_Float16)wb.x; bf[5] = (_Float16)wb.y; bf[6] = (_Float16)wb.z; bf[7] = (_Float16)wb.w;
            acc[nt] = mfma16(af, bf, acc[nt]);
        }
    }

    float as[4], ad[4];
#pragma unroll
    for (int nt = 0; nt < 4; ++nt) {
        const int d = nt * 16 + dlow;
        as[nt] = asrc[head * 64 + d];
        ad[nt] = adst[head * 64 + d];
    }
    float es[4], ed[4];
#pragma unroll
    for (int r = 0; r < 4; ++r) {
        float se = 0.f, de = 0.f;
#pragma unroll
        for (int nt = 0; nt < 4; ++nt) { se += acc[nt][r] * as[nt]; de += acc[nt][r] * ad[nt]; }
#pragma unroll
        for (int m = 1; m < 16; m <<= 1) { se += __shfl_xor(se, m); de += __shfl_xor(de, m); }
        es[r] = se; ed[r] = de;
    }
    if (dlow == 0) {
#pragma unroll
        for (int r = 0; r < 4; ++r) {
            const int j = rowbase + q * 4 + r;
            esrc[j * GAT_H + head] = es[r];
            ddata[(size_t)head * GAT_N + j] = ed[r] * L2E;
        }
    }

    // Hpack: element (j, d) -> [head][j>>5][nt][(p>>3)*16 + dlow][p&7], p=j&31.
    const int jc = rowbase >> 5;
    const int p16 = rowbase & 16;
#pragma unroll
    for (int nt = 0; nt < 4; ++nt) {
#pragma unroll
        for (int rp = 0; rp < 4; rp += 2) {
            const int p = p16 + q * 4 + rp;
            const int qp = p >> 3, e = p & 7;
            const int lanep = qp * 16 + dlow;
            const size_t idx = ((((size_t)head * 128 + jc) * 4 + nt) * 64 + lanep) * 8 + e;
            union { unsigned u; _Float16 h[2]; } pk;
            pk.h[0] = (_Float16)acc[nt][rp];
            pk.h[1] = (_Float16)acc[nt][rp + 1];
            *(unsigned*)(Hpack + idx) = pk.u;
        }
    }
}

// -------- Phase A2: per-i and per-j exponential factor tables ---------------
// grid 128 = 8 heads x 16 slices. Each block redundantly reduces its head's
// max over ddata (scaled by log2e; same argmax), then fills its 256-entry
// slice. No atomics, no init dependency.
__global__ __launch_bounds__(256) void gat_ftab(
    const float* __restrict__ esrc, const float* __restrict__ ddata,
    unsigned* __restrict__ Epk1, unsigned* __restrict__ Epk2,
    _Float16* __restrict__ F1, _Float16* __restrict__ F2)
{
    __shared__ float wmax[4];
    const int bid = blockIdx.x;
    const int tid = threadIdx.x;
    const int head = bid >> 4;
    const float* dh = ddata + head * GAT_N;

    // per-head max of ddata (= max_ed * log2e)
    float m = -3.4e38f;
    {
        const v4f* dp = (const v4f*)(dh + tid * 16);
#pragma unroll
        for (int k = 0; k < 4; ++k) {
            v4f v = dp[k];
            m = fmaxf(m, fmaxf(fmaxf(v[0], v[1]), fmaxf(v[2], v[3])));
        }
    }
#pragma unroll
    for (int s = 1; s < 64; s <<= 1) m = fmaxf(m, __shfl_xor(m, s));
    if ((tid & 63) == 0) wmax[tid >> 6] = m;
    __syncthreads();
    const float Dml = fmaxf(fmaxf(wmax[0], wmax[1]), fmaxf(wmax[2], wmax[3]));
    const float Dm = Dml * LN2;                     // unscale: /log2e

    const int i = (bid & 15) * 256 + tid;
    const int idx = head * GAT_N + i;
    const float s = esrc[i * GAT_H + head];
    const float sm = s + Dm;
    const float M = fmaxf(sm, 0.2f * sm);
    const float e1 = __builtin_amdgcn_exp2f((sm - M) * L2E);
    const float e2 = __builtin_amdgcn_exp2f((0.2f * sm - M) * L2E);
    union { _Float16 h[2]; unsigned u; } pk;
    pk.h[0] = (_Float16)e1; pk.h[1] = (_Float16)e1; Epk1[idx] = pk.u;
    pk.h[0] = (_Float16)e2; pk.h[1] = (_Float16)e2; Epk2[idx] = pk.u;
    const float dl = dh[i] - Dml;                   // (d - Dm)*log2e
    F1[idx] = (_Float16)__builtin_amdgcn_exp2f(dl);
    F2[idx] = (_Float16)__builtin_amdgcn_exp2f(0.2f * dl);
}

// ---------------- Phase B: fused mask + softmax + alpha@H -------------------
// grid 512 = (it = bid>>3, 64 rows) x (head = bid&7 -> XCD-pinned).
// block 256 (4 waves): ALL waves hold the full 64-row i-tile (4 E-pairs);
// wave wv takes jc chunks with jc%4 == wv -> each Hpack chunk loaded ONCE
// per block. No barriers in main loop; reg double-buffer; LDS tree combine.
__global__ __launch_bounds__(256, 2) void gat_attn(
    const unsigned* __restrict__ maskw, const _Float16* __restrict__ Hpack,
    const unsigned* __restrict__ Epk1, const unsigned* __restrict__ Epk2,
    const _Float16* __restrict__ F1, const _Float16* __restrict__ F2,
    const float* __restrict__ bias, float* __restrict__ out)
{
    // mask mlds[64 rows][132 words] (33.8 KB) unioned with xchg[2][64][81] (41.5 KB)
    __shared__ __align__(16) char smem[2 * 64 * 81 * 4];
    unsigned (*mlds)[132] = (unsigned (*)[132])smem;
    float* xch = (float*)smem;

    const int bid = blockIdx.x;
    const int head = bid & 7;
    const int it = bid >> 3;
    const int tid = threadIdx.x;
    const int wv = tid >> 6, l = tid & 63;
    const int dlow = l & 15, q = l >> 4, qs = q * 8;
    const int ibase = it * 64;

    // stage 64-row mask: mlds[row][word], thread t -> row t>>2, 32 words
    {
        const int r = tid >> 2;
        const int wq = (tid & 3) * 32;
        const unsigned* mp = maskw + (size_t)(ibase + r) * 128 + wq;
#pragma unroll
        for (int k = 0; k < 8; ++k) {
            v4i a = *(const v4i*)(mp + k * 4);
            *(v4i*)&mlds[r][wq + k * 4] = a;
        }
    }

    f16x2 E1p[4], E2p[4];
#pragma unroll
    for (int g = 0; g < 4; ++g) {
        E1p[g] = __builtin_bit_cast(f16x2, Epk1[head * GAT_N + ibase + g * 16 + dlow]);
        E2p[g] = __builtin_bit_cast(f16x2, Epk2[head * GAT_N + ibase + g * 16 + dlow]);
    }

    v4f accW[4][4] = {};
    v4f accZ[4] = {};
    v8h ones;
#pragma unroll
    for (int e = 0; e < 8; ++e) ones[e] = (_Float16)1.0f;

    const _Float16* Hl = Hpack + (size_t)head * 262144 + (size_t)l * 8;
    const _Float16* F1h = F1 + head * GAT_N;
    const _Float16* F2h = F2 + head * GAT_N;

    __syncthreads();   // mask visible; no barriers until epilogue

    unsigned Amw[4], Bmw[4];
    v4i Af1, Af2, Bf1, Bf2;
    v8h Ah[4], Bh[4];

#define GAT_LOAD(P, T) {                                                     \
        const int jc_ = (T) * 4 + wv;                                        \
        _Pragma("unroll")                                                    \
        for (int g = 0; g < 4; ++g) P##mw[g] = mlds[g * 16 + dlow][jc_];     \
        const int kg_ = (jc_ << 5) + qs;                                     \
        P##f1 = *(const v4i*)(F1h + kg_);                                    \
        P##f2 = *(const v4i*)(F2h + kg_);                                    \
        const _Float16* hp_ = Hl + (size_t)jc_ * 2048;                       \
        P##h[0] = *(const v8h*)(hp_);                                        \
        P##h[1] = *(const v8h*)(hp_ + 512);                                  \
        P##h[2] = *(const v8h*)(hp_ + 1024);                                 \
        P##h[3] = *(const v8h*)(hp_ + 1536);                                 \
    }

    // byte-smear (4-bit fields only -> carry-free; see R8 note)
#define GAT_COMP(P) {                                                        \
        _Pragma("unroll")                                                    \
        for (int g = 0; g < 4; ++g) {                                        \
            const unsigned b8_ = (P##mw[g] >> qs) & 255u;                    \
            const unsigned z1_ = (((b8_ & 15u) * 0x204081u) << 7) & 0x80808080u; \
            const unsigned z2_ = (((b8_ >> 4) * 0x204081u) << 7) & 0x80808080u;  \
            const unsigned m1_ = (z1_ >> 7) * 255u;                          \
            const unsigned m2_ = (z2_ >> 7) * 255u;                          \
            U8 fr_;                                                          \
            fr_.w[0] = (int)(pmax2(E1p[g], E2p[g], P##f1[0], P##f2[0])       \
                             & __builtin_amdgcn_perm(0u, m1_, 0x01010000u)); \
            fr_.w[1] = (int)(pmax2(E1p[g], E2p[g], P##f1[1], P##f2[1])       \
                             & __builtin_amdgcn_perm(0u, m1_, 0x03030202u)); \
            fr_.w[2] = (int)(pmax2(E1p[g], E2p[g], P##f1[2], P##f2[2])       \
                             & __builtin_amdgcn_perm(0u, m2_, 0x01010000u)); \
            fr_.w[3] = (int)(pmax2(E1p[g], E2p[g], P##f1[3], P##f2[3])       \
                             & __builtin_amdgcn_perm(0u, m2_, 0x03030202u)); \
            accW[g][0] = mfma16(fr_.h, P##h[0], accW[g][0]);                 \
            accW[g][1] = mfma16(fr_.h, P##h[1], accW[g][1]);                 \
            accW[g][2] = mfma16(fr_.h, P##h[2], accW[g][2]);                 \
            accW[g][3] = mfma16(fr_.h, P##h[3], accW[g][3]);                 \
            accZ[g]    = mfma16(fr_.h, ones,  accZ[g]);                      \
        }                                                                    \
    }

    GAT_LOAD(A, 0)
    for (int t = 0; t < 30; t += 2) {
        GAT_LOAD(B, t + 1)
        GAT_COMP(A)
        GAT_LOAD(A, t + 2)
        GAT_COMP(B)
    }
    GAT_LOAD(B, 31)
    GAT_COMP(A)
    GAT_COMP(B)
#undef GAT_LOAD
#undef GAT_COMP

    // ---- 4-way j-partial combine: tree through LDS (reuses mask space) ----
    __syncthreads();
    {
        float* xb = xch + ((size_t)(wv >> 1) * 64 + l) * 81;
        if (wv & 1) {   // waves 1,3 write
#pragma unroll
            for (int g = 0; g < 4; ++g) {
#pragma unroll
                for (int nt = 0; nt < 4; ++nt)
#pragma unroll
                    for (int r = 0; r < 4; ++r) xb[(g * 4 + nt) * 4 + r] = accW[g][nt][r];
#pragma unroll
                for (int r = 0; r < 4; ++r) xb[64 + g * 4 + r] = accZ[g][r];
            }
        }
        __syncthreads();
        if (!(wv & 1)) {   // waves 0,2 reduce
#pragma unroll
            for (int g = 0; g < 4; ++g) {
#pragma unroll
                for (int nt = 0; nt < 4; ++nt)
#pragma unroll
                    for (int r = 0; r < 4; ++r) accW[g][nt][r] += xb[(g * 4 + nt) * 4 + r];
#pragma unroll
                for (int r = 0; r < 4; ++r) accZ[g][r] += xb[64 + g * 4 + r];
            }
        }
        __syncthreads();
        float* x0 = xch + (size_t)l * 81;
        if (wv == 2) {   // wave 2 writes its reduced partial
#pragma unroll
            for (int g = 0; g < 4; ++g) {
#pragma unroll
                for (int nt = 0; nt < 4; ++nt)
#pragma unroll
                    for (int r = 0; r < 4; ++r) x0[(g * 4 + nt) * 4 + r] = accW[g][nt][r];
#pragma unroll
                for (int r = 0; r < 4; ++r) x0[64 + g * 4 + r] = accZ[g][r];
            }
        }
        __syncthreads();
        if (wv == 0) {
#pragma unroll
            for (int g = 0; g < 4; ++g) {
#pragma unroll
                for (int nt = 0; nt < 4; ++nt)
#pragma unroll
                    for (int r = 0; r < 4; ++r) accW[g][nt][r] += x0[(g * 4 + nt) * 4 + r];
#pragma unroll
                for (int r = 0; r < 4; ++r) accZ[g][r] += x0[64 + g * 4 + r];
            }
#pragma unroll
            for (int g = 0; g < 4; ++g) {
                float zi[4];
#pragma unroll
                for (int r = 0; r < 4; ++r) zi[r] = 1.0f / accZ[g][r];
#pragma unroll
                for (int nt = 0; nt < 4; ++nt) {
                    const int col = head * 64 + nt * 16 + dlow;
                    const float b = bias[col];
#pragma unroll
                    for (int r = 0; r < 4; ++r) {
                        const int row = ibase + g * 16 + q * 4 + r;
                        out[(size_t)row * GAT_C + col] = accW[g][nt][r] * zi[r] + b;
                    }
                }
            }
        }
    }
}

extern "C" void kernel_launch(void* const* d_in, const int* in_sizes, int n_in,
                              void* d_out, int out_size, void* d_ws, size_t ws_size,
                              hipStream_t stream) {
    const float* x    = (const float*)d_in[0];
    const int*   adj  = (const int*)d_in[1];
    const float* W    = (const float*)d_in[2];
    const float* asrc = (const float*)d_in[3];
    const float* adst = (const float*)d_in[4];
    const float* bias = (const float*)d_in[5];
    float* out = (float*)d_out;

    char* ws = (char*)d_ws;                     // needs ~6.7 MB
    _Float16* Hpack  = (_Float16*)ws;                               // 4 MB
    unsigned* maskw  = (unsigned*)(ws + (4u << 20));                // 2 MB
    float*    ddata  = (float*)(ws + (6u << 20));                   // 128 KB
    float*    esrc   = (float*)(ws + (6u << 20) + (128u << 10));    // 128 KB
    unsigned* Epk1   = (unsigned*)(ws + (6u << 20) + (256u << 10)); // 128 KB
    unsigned* Epk2   = (unsigned*)(ws + (6u << 20) + (384u << 10)); // 128 KB
    _Float16* F1     = (_Float16*)(ws + (6u << 20) + (512u << 10)); // 64 KB
    _Float16* F2     = (_Float16*)(ws + (6u << 20) + (576u << 10)); // 64 KB

    hipLaunchKernelGGL(gat_prep, dim3(2560), dim3(256), 0, stream,
                       x, W, asrc, adst, adj, Hpack, ddata, esrc, maskw);
    hipLaunchKernelGGL(gat_ftab, dim3(128), dim3(256), 0, stream,
                       esrc, ddata, Epk1, Epk2, F1, F2);
    hipLaunchKernelGGL(gat_attn, dim3(512), dim3(256), 0, stream,
                       maskw, Hpack, Epk1, Epk2, F1, F2, bias, out);
}